// Round 4
// baseline (991.493 us; speedup 1.0000x reference)
//
#include <hip/hip_runtime.h>
#include <hip/hip_fp16.h>
#include <stdint.h>

// VM-factorized voxel grid: N pts -> 48 feats (3 planes x 16ch) -> 27 outputs.
// Pipeline: memset hist -> prep (fused: planes/lines -> fp16 channel-last, basis pad,
// 4-pt/thread histogram) -> scan -> 4-pt/thread scatter -> eval
// (fp16 gathers, packed-f32 interp + matmul, scattered 27-dword store).

constexpr int NPTS = 2097152;
constexpr int CCH  = 16;
constexpr int RES  = 320;
constexpr long long HW = (long long)RES * RES;   // 102400
constexpr int FD   = 27;
constexpr int BLK  = 256;
constexpr int NCELL = 32768;                     // 32^3 Morton cells

constexpr int HIST_BLOCKS = NPTS / (BLK * 4);    // 2048
constexpr int PLANE_BLOCKS = 1200;               // 3 * 400
constexpr int LINE_BLOCKS = 4;

// ---- workspace layout (bytes), all 16B-aligned ----
constexpr size_t WS_PLANEH = 0;                                   // 3*HW*16*2 = 9,830,400
constexpr size_t WS_LINEH  = WS_PLANEH + 3ull*HW*CCH*2;           // 30,720
constexpr size_t WS_BPAD   = WS_LINEH + 3ull*RES*CCH*2;           // 5,376
constexpr size_t WS_HIST   = WS_BPAD + 48ull*14*8;                // 131,072
constexpr size_t WS_CURSOR = WS_HIST + (size_t)NCELL*4;           // 131,072
constexpr size_t WS_SORTED = WS_CURSOR + (size_t)NCELL*4;         // N*16
constexpr size_t WS_NEED   = WS_SORTED + (size_t)NPTS*16;         // ~43.7 MB

// ---------------- helpers ----------------
__device__ __forceinline__ unsigned spread5(unsigned v) {
    return (v & 1u) | ((v & 2u) << 2) | ((v & 4u) << 4) | ((v & 8u) << 6) | ((v & 16u) << 8);
}
__device__ __forceinline__ int cell_key(float px, float py, float pz) {
    int cx = min(max((int)((px + 1.f) * 16.f), 0), 31);
    int cy = min(max((int)((py + 1.f) * 16.f), 0), 31);
    int cz = min(max((int)((pz + 1.f) * 16.f), 0), 31);
    return (int)(spread5((unsigned)cx) | (spread5((unsigned)cy) << 1) | (spread5((unsigned)cz) << 2));
}

// packed fp32 ops (VOP3P). b from SGPR pair for the basis (uniform), VGPR otherwise.
__device__ __forceinline__ void pk_fma_s(float2& acc, const float2 ab, const float2 b) {
    unsigned long long bs;
    __builtin_memcpy(&bs, &b, 8);
    asm("v_pk_fma_f32 %0, %1, %2, %0" : "+v"(acc) : "v"(ab), "s"(bs));
}
__device__ __forceinline__ float2 pk_mul(float2 a, float2 b) {
    float2 d; asm("v_pk_mul_f32 %0, %1, %2" : "=v"(d) : "v"(a), "v"(b)); return d;
}
__device__ __forceinline__ float2 pk_fma(float2 a, float2 b, float2 c) {
    float2 d; asm("v_pk_fma_f32 %0, %1, %2, %3" : "=v"(d) : "v"(a), "v"(b), "v"(c)); return d;
}

__device__ __forceinline__ float2 h2f(unsigned u) {
    __half2 h = *(__half2*)&u;
    return __half22float2(h);
}
__device__ __forceinline__ unsigned lane_of(uint4 q, int j) {
    return j == 0 ? q.x : (j == 1 ? q.y : (j == 2 ? q.z : q.w));
}

// ---------------- prep: hist (4 pts/thread) + planes/lines fp16 + basis pad ----------------
__global__ __launch_bounds__(BLK) void prep_kernel(
    const float* __restrict__ pts,
    const float* __restrict__ pxy, const float* __restrict__ pxz, const float* __restrict__ pyz,
    const float* __restrict__ vx, const float* __restrict__ vy, const float* __restrict__ vz,
    const float* __restrict__ basis,
    __half* __restrict__ planesH, __half* __restrict__ linesH, float2* __restrict__ bpad,
    unsigned* __restrict__ hist) {
    const int bid = blockIdx.x;
    const int tid = threadIdx.x;
    if (bid < HIST_BLOCKS) {                // 4-point histogram
        const int t = bid * BLK + tid;
        const float4* p4 = (const float4*)pts;
        const float4 f0 = p4[t*3+0], f1 = p4[t*3+1], f2 = p4[t*3+2];
        atomicAdd(&hist[cell_key(f0.x, f0.y, f0.z)], 1u);
        atomicAdd(&hist[cell_key(f0.w, f1.x, f1.y)], 1u);
        atomicAdd(&hist[cell_key(f1.z, f1.w, f2.x)], 1u);
        atomicAdd(&hist[cell_key(f2.y, f2.z, f2.w)], 1u);
    } else if (bid < HIST_BLOCKS + PLANE_BLOCKS) {   // planes -> fp16 channel-last
        const int pb = bid - HIST_BLOCKS;
        const int plane = pb / 400;
        const int texel = (pb % 400) * BLK + tid;
        const float* src = (plane == 0) ? pxy : (plane == 1 ? pxz : pyz);
        union { ushort u[16]; uint4 q[2]; } pk;
        #pragma unroll
        for (int c = 0; c < CCH; ++c)
            pk.u[c] = __half_as_ushort(__float2half(src[(size_t)c * HW + texel]));
        uint4* dst = (uint4*)(planesH + ((size_t)plane * HW + texel) * CCH);
        dst[0] = pk.q[0]; dst[1] = pk.q[1];
    } else if (bid < HIST_BLOCKS + PLANE_BLOCKS + LINE_BLOCKS) {  // lines
        const int idx = (bid - HIST_BLOCKS - PLANE_BLOCKS) * BLK + tid;
        if (idx >= 3 * RES) return;
        const int axis = idx / RES, t = idx % RES;
        const float* src = (axis == 0) ? vx : (axis == 1 ? vy : vz);
        union { ushort u[16]; uint4 q[2]; } pk;
        #pragma unroll
        for (int c = 0; c < CCH; ++c)
            pk.u[c] = __half_as_ushort(__float2half(src[c * RES + t]));
        uint4* dst = (uint4*)(linesH + ((size_t)axis * RES + t) * CCH);
        dst[0] = pk.q[0]; dst[1] = pk.q[1];
    } else {                                // basis (48,27) -> padded float2 (48,14)
        for (int k = tid; k < 48 * 14; k += BLK) {
            const int r = k / 14, f = k % 14;
            float x = basis[r * FD + 2 * f];
            float y = (2 * f + 1 < FD) ? basis[r * FD + 2 * f + 1] : 0.f;
            bpad[k] = make_float2(x, y);
        }
    }
}

// ---------------- scan ----------------
__global__ __launch_bounds__(1024) void scan_kernel(const unsigned* __restrict__ hist,
                                                    unsigned* __restrict__ cursor) {
    __shared__ unsigned lsum[1024];
    const int t = threadIdx.x;
    const int base = t * 32;
    const uint4* h4 = (const uint4*)(hist + base);
    unsigned local[32];
    unsigned run = 0;
    #pragma unroll
    for (int q = 0; q < 8; ++q) {
        uint4 v = h4[q];
        local[4*q+0] = run; run += v.x;
        local[4*q+1] = run; run += v.y;
        local[4*q+2] = run; run += v.z;
        local[4*q+3] = run; run += v.w;
    }
    lsum[t] = run;
    __syncthreads();
    for (int o = 1; o < 1024; o <<= 1) {
        unsigned v = (t >= o) ? lsum[t - o] : 0u;
        __syncthreads();
        lsum[t] += v;
        __syncthreads();
    }
    const unsigned b = lsum[t] - run;
    uint4* c4 = (uint4*)(cursor + base);
    #pragma unroll
    for (int q = 0; q < 8; ++q)
        c4[q] = make_uint4(b + local[4*q+0], b + local[4*q+1], b + local[4*q+2], b + local[4*q+3]);
}

// ---------------- scatter (4 pts/thread) ----------------
__global__ __launch_bounds__(BLK) void scatter_kernel(const float* __restrict__ pts,
                                                      unsigned* __restrict__ cursor,
                                                      float4* __restrict__ sorted) {
    const int t = blockIdx.x * BLK + threadIdx.x;
    const float4* p4 = (const float4*)pts;
    const float4 f0 = p4[t*3+0], f1 = p4[t*3+1], f2 = p4[t*3+2];
    const int i0 = 4 * t;
    const unsigned pos0 = atomicAdd(&cursor[cell_key(f0.x, f0.y, f0.z)], 1u);
    const unsigned pos1 = atomicAdd(&cursor[cell_key(f0.w, f1.x, f1.y)], 1u);
    const unsigned pos2 = atomicAdd(&cursor[cell_key(f1.z, f1.w, f2.x)], 1u);
    const unsigned pos3 = atomicAdd(&cursor[cell_key(f2.y, f2.z, f2.w)], 1u);
    sorted[pos0] = make_float4(f0.x, f0.y, f0.z, __int_as_float(i0 + 0));
    sorted[pos1] = make_float4(f0.w, f1.x, f1.y, __int_as_float(i0 + 1));
    sorted[pos2] = make_float4(f1.z, f1.w, f2.x, __int_as_float(i0 + 2));
    sorted[pos3] = make_float4(f2.y, f2.z, f2.w, __int_as_float(i0 + 3));
}

// ---------------- eval ----------------
__device__ __forceinline__ void do_half(const uint4* __restrict__ P, const uint4* __restrict__ L,
                                        int t00, int t01, int t10, int t11, int l0, int l1,
                                        float wc, float wr, float lw, int h, int rbase,
                                        const float2* __restrict__ bp, float2 acc[14]) {
    const uint4 c00 = P[2*t00 + h], c01 = P[2*t01 + h];
    const uint4 c10 = P[2*t10 + h], c11 = P[2*t11 + h];
    const uint4 la4 = L[2*l0 + h],  lb4 = L[2*l1 + h];
    const float w00 = (1.f - wc) * (1.f - wr), w01 = wc * (1.f - wr);
    const float w10 = (1.f - wc) * wr,         w11 = wc * wr;
    const float2 w00_2 = make_float2(w00, w00), w01_2 = make_float2(w01, w01);
    const float2 w10_2 = make_float2(w10, w10), w11_2 = make_float2(w11, w11);
    const float2 lw2   = make_float2(lw, lw),   mlw2  = make_float2(1.f - lw, 1.f - lw);
    #pragma unroll
    for (int j = 0; j < 4; ++j) {
        const float2 v00 = h2f(lane_of(c00, j)), v01 = h2f(lane_of(c01, j));
        const float2 v10 = h2f(lane_of(c10, j)), v11 = h2f(lane_of(c11, j));
        float2 s = pk_mul(v00, w00_2);
        s = pk_fma(v01, w01_2, s);
        s = pk_fma(v10, w10_2, s);
        s = pk_fma(v11, w11_2, s);
        const float2 la = h2f(lane_of(la4, j)), lb = h2f(lane_of(lb4, j));
        float2 l = pk_mul(la, mlw2);
        l = pk_fma(lb, lw2, l);
        s = pk_mul(s, l);
        const int r0 = rbase + 8 * h + 2 * j;
        const float2 fx2 = make_float2(s.x, s.x);
        #pragma unroll
        for (int f = 0; f < 14; ++f) pk_fma_s(acc[f], fx2, bp[r0 * 14 + f]);
        const float2 fy2 = make_float2(s.y, s.y);
        #pragma unroll
        for (int f = 0; f < 14; ++f) pk_fma_s(acc[f], fy2, bp[(r0 + 1) * 14 + f]);
    }
}

__global__ __launch_bounds__(BLK, 8) void eval_kernel(
    const float4* __restrict__ sorted,
    const __half* __restrict__ planesH,
    const __half* __restrict__ linesH,
    const float2* __restrict__ bp,
    float* __restrict__ out) {
    constexpr int NBLK = NPTS / BLK;            // 8192
    constexpr int CHUNK = NBLK / 8;             // 1024
    const int bid = blockIdx.x;
    const int swz = (bid & 7) * CHUNK + (bid >> 3);   // contiguous sorted range per XCD
    const int j = swz * BLK + threadIdx.x;

    const float4 pt = sorted[j];
    const float px = pt.x, py = pt.y, pz = pt.z;
    const long long oi = (long long)__float_as_int(pt.w);

    const float scl = 0.5f * (RES - 1);
    const float fx = (px + 1.f) * scl, fy = (py + 1.f) * scl, fz = (pz + 1.f) * scl;
    const float xf = floorf(fx), yf = floorf(fy), zf = floorf(fz);
    const float wx = fx - xf, wy = fy - yf, wz = fz - zf;
    int x0 = min(max((int)xf, 0), RES - 1);
    int y0 = min(max((int)yf, 0), RES - 1);
    int z0 = min(max((int)zf, 0), RES - 1);
    const int x1 = min(x0 + 1, RES - 1);
    const int y1 = min(y0 + 1, RES - 1);
    const int z1 = min(z0 + 1, RES - 1);

    const uint4* Pxy = (const uint4*)planesH;
    const uint4* Pxz = (const uint4*)(planesH + (size_t)HW * CCH);
    const uint4* Pyz = (const uint4*)(planesH + (size_t)2 * HW * CCH);
    const uint4* Lx = (const uint4*)linesH;
    const uint4* Ly = (const uint4*)(linesH + (size_t)RES * CCH);
    const uint4* Lz = (const uint4*)(linesH + (size_t)2 * RES * CCH);

    float2 acc[14];
    #pragma unroll
    for (int f = 0; f < 14; ++f) acc[f] = make_float2(0.f, 0.f);

    do_half(Pxy, Lz, y0*RES+x0, y0*RES+x1, y1*RES+x0, y1*RES+x1, z0, z1, wx, wy, wz, 0,  0, bp, acc);
    do_half(Pxy, Lz, y0*RES+x0, y0*RES+x1, y1*RES+x0, y1*RES+x1, z0, z1, wx, wy, wz, 1,  0, bp, acc);
    do_half(Pxz, Ly, z0*RES+x0, z0*RES+x1, z1*RES+x0, z1*RES+x1, y0, y1, wx, wz, wy, 0, 16, bp, acc);
    do_half(Pxz, Ly, z0*RES+x0, z0*RES+x1, z1*RES+x0, z1*RES+x1, y0, y1, wx, wz, wy, 1, 16, bp, acc);
    do_half(Pyz, Lx, z0*RES+y0, z0*RES+y1, z1*RES+y0, z1*RES+y1, x0, x1, wy, wz, wx, 0, 32, bp, acc);
    do_half(Pyz, Lx, z0*RES+y0, z0*RES+y1, z1*RES+y0, z1*RES+y1, x0, x1, wy, wz, wx, 1, 32, bp, acc);

    float* op = out + oi * FD;
    #pragma unroll
    for (int f = 0; f < 14; ++f) {
        op[2*f] = acc[f].x;
        if (2*f + 1 < FD) op[2*f + 1] = acc[f].y;
    }
}

// ---------------- fallback (no workspace) ----------------
__device__ __forceinline__ float bilerp(const float* __restrict__ p,
                                        int o00, int o01, int o10, int o11,
                                        float wc, float wr) {
    float v00 = p[o00], v01 = p[o01], v10 = p[o10], v11 = p[o11];
    float top = v00 + wc * (v01 - v00);
    float bot = v10 + wc * (v11 - v10);
    return top + wr * (bot - top);
}

__global__ __launch_bounds__(BLK) void vm_eval_fallback(
    const float* __restrict__ pts,
    const float* __restrict__ pxy, const float* __restrict__ pyz, const float* __restrict__ pxz,
    const float* __restrict__ vx, const float* __restrict__ vy, const float* __restrict__ vz,
    const float* __restrict__ basis, float* __restrict__ out) {
    const long long i = (long long)blockIdx.x * BLK + threadIdx.x;
    const float px = pts[i*3], py = pts[i*3+1], pz = pts[i*3+2];
    const float scl = 0.5f * (RES - 1);
    const float fx = (px + 1.f) * scl, fy = (py + 1.f) * scl, fz = (pz + 1.f) * scl;
    const float xf = floorf(fx), yf = floorf(fy), zf = floorf(fz);
    const float wx = fx - xf, wy = fy - yf, wz = fz - zf;
    int x0 = min(max((int)xf, 0), RES - 1);
    int y0 = min(max((int)yf, 0), RES - 1);
    int z0 = min(max((int)zf, 0), RES - 1);
    const int x1 = min(x0+1, RES-1), y1 = min(y0+1, RES-1), z1 = min(z0+1, RES-1);
    float acc[FD];
    #pragma unroll
    for (int f = 0; f < FD; ++f) acc[f] = 0.f;
    #pragma unroll 4
    for (int c = 0; c < CCH; ++c) {
        const float* a = pxy + c * HW;
        const float* b = pxz + c * HW;
        const float* d = pyz + c * HW;
        float lz = vz[c*RES+z0]; lz += wz * (vz[c*RES+z1] - lz);
        float ly = vy[c*RES+y0]; ly += wy * (vy[c*RES+y1] - ly);
        float lx = vx[c*RES+x0]; lx += wx * (vx[c*RES+x1] - lx);
        const float fa = bilerp(a, y0*RES+x0, y0*RES+x1, y1*RES+x0, y1*RES+x1, wx, wy) * lz;
        const float fb = bilerp(b, z0*RES+x0, z0*RES+x1, z1*RES+x0, z1*RES+x1, wx, wz) * ly;
        const float fc = bilerp(d, z0*RES+y0, z0*RES+y1, z1*RES+y0, z1*RES+y1, wy, wz) * lx;
        #pragma unroll
        for (int f = 0; f < FD; ++f)
            acc[f] += fa * basis[c*FD+f] + fb * basis[(CCH+c)*FD+f] + fc * basis[(2*CCH+c)*FD+f];
    }
    float* op = out + i * FD;
    #pragma unroll
    for (int f = 0; f < FD; ++f) op[f] = acc[f];
}

extern "C" void kernel_launch(void* const* d_in, const int* in_sizes, int n_in,
                              void* d_out, int out_size, void* d_ws, size_t ws_size,
                              hipStream_t stream) {
    const float* pts   = (const float*)d_in[0];
    const float* pxy   = (const float*)d_in[1];
    const float* pyz   = (const float*)d_in[2];
    const float* pxz   = (const float*)d_in[3];
    const float* vx    = (const float*)d_in[4];
    const float* vy    = (const float*)d_in[5];
    const float* vz    = (const float*)d_in[6];
    const float* basis = (const float*)d_in[7];
    float* out = (float*)d_out;

    if (ws_size < WS_NEED) {
        vm_eval_fallback<<<NPTS / BLK, BLK, 0, stream>>>(pts, pxy, pyz, pxz, vx, vy, vz, basis, out);
        return;
    }

    uint8_t* w = (uint8_t*)d_ws;
    __half*   planesH = (__half*)(w + WS_PLANEH);
    __half*   linesH  = (__half*)(w + WS_LINEH);
    float2*   bpad    = (float2*)(w + WS_BPAD);
    unsigned* hist    = (unsigned*)(w + WS_HIST);
    unsigned* cursor  = (unsigned*)(w + WS_CURSOR);
    float4*   sorted  = (float4*)(w + WS_SORTED);

    hipMemsetAsync(hist, 0, (size_t)NCELL * 4, stream);
    prep_kernel<<<HIST_BLOCKS + PLANE_BLOCKS + LINE_BLOCKS + 1, BLK, 0, stream>>>(
        pts, pxy, pxz, pyz, vx, vy, vz, basis, planesH, linesH, bpad, hist);
    scan_kernel<<<1, 1024, 0, stream>>>(hist, cursor);
    scatter_kernel<<<NPTS / (BLK * 4), BLK, 0, stream>>>(pts, cursor, sorted);
    eval_kernel<<<NPTS / BLK, BLK, 0, stream>>>(sorted, planesH, linesH, bpad, out);
}

// Round 5
// 550.894 us; speedup vs baseline: 1.7998x; 1.7998x over previous
//
#include <hip/hip_runtime.h>
#include <hip/hip_fp16.h>
#include <stdint.h>

// VM-factorized voxel grid: N pts -> 48 feats (3 planes x 16ch) -> 27 outputs.
// Pipeline: memset hist -> prep (planes/lines -> fp16 channel-last, basis pad,
// 4-pt/thread histogram into 8 XCD-local hist copies) -> scan (per-copy cursors)
// -> 4-pt/thread scatter (XCD-local cursor atomics) -> eval
// (fp16 gathers, packed-f32 interp + matmul, scattered 27-dword store).

constexpr int NPTS = 2097152;
constexpr int CCH  = 16;
constexpr int RES  = 320;
constexpr long long HW = (long long)RES * RES;   // 102400
constexpr int FD   = 27;
constexpr int BLK  = 256;
constexpr int NCELL = 32768;                     // 32^3 Morton cells
constexpr int NHIST = 8;                         // one hist copy per XCD

constexpr int HIST_BLOCKS = NPTS / (BLK * 4);    // 2048
constexpr int PLANE_BLOCKS = 1200;               // 3 * 400
constexpr int LINE_BLOCKS = 4;

// ---- workspace layout (bytes), all 16B-aligned ----
constexpr size_t WS_PLANEH = 0;                                   // 3*HW*16*2 = 9,830,400
constexpr size_t WS_LINEH  = WS_PLANEH + 3ull*HW*CCH*2;           // 30,720
constexpr size_t WS_BPAD   = WS_LINEH + 3ull*RES*CCH*2;           // 5,376
constexpr size_t WS_HIST   = WS_BPAD + 48ull*14*8;                // 8*131,072 = 1 MB
constexpr size_t WS_CURSOR = WS_HIST + (size_t)NHIST*NCELL*4;     // 1 MB
constexpr size_t WS_SORTED = WS_CURSOR + (size_t)NHIST*NCELL*4;   // N*16
constexpr size_t WS_NEED   = WS_SORTED + (size_t)NPTS*16;         // ~45.4 MB

// ---------------- helpers ----------------
__device__ __forceinline__ unsigned spread5(unsigned v) {
    return (v & 1u) | ((v & 2u) << 2) | ((v & 4u) << 4) | ((v & 8u) << 6) | ((v & 16u) << 8);
}
__device__ __forceinline__ int cell_key(float px, float py, float pz) {
    int cx = min(max((int)((px + 1.f) * 16.f), 0), 31);
    int cy = min(max((int)((py + 1.f) * 16.f), 0), 31);
    int cz = min(max((int)((pz + 1.f) * 16.f), 0), 31);
    return (int)(spread5((unsigned)cx) | (spread5((unsigned)cy) << 1) | (spread5((unsigned)cz) << 2));
}

// packed fp32 ops (VOP3P). b from SGPR pair for the basis (uniform), VGPR otherwise.
__device__ __forceinline__ void pk_fma_s(float2& acc, const float2 ab, const float2 b) {
    unsigned long long bs;
    __builtin_memcpy(&bs, &b, 8);
    asm("v_pk_fma_f32 %0, %1, %2, %0" : "+v"(acc) : "v"(ab), "s"(bs));
}
__device__ __forceinline__ float2 pk_mul(float2 a, float2 b) {
    float2 d; asm("v_pk_mul_f32 %0, %1, %2" : "=v"(d) : "v"(a), "v"(b)); return d;
}
__device__ __forceinline__ float2 pk_fma(float2 a, float2 b, float2 c) {
    float2 d; asm("v_pk_fma_f32 %0, %1, %2, %3" : "=v"(d) : "v"(a), "v"(b), "v"(c)); return d;
}

__device__ __forceinline__ float2 h2f(unsigned u) {
    __half2 h = *(__half2*)&u;
    return __half22float2(h);
}
__device__ __forceinline__ unsigned lane_of(uint4 q, int j) {
    return j == 0 ? q.x : (j == 1 ? q.y : (j == 2 ? q.z : q.w));
}

// ---------------- prep: hist (4 pts/thread, XCD-local copy) + planes/lines fp16 + basis pad ----------------
__global__ __launch_bounds__(BLK) void prep_kernel(
    const float* __restrict__ pts,
    const float* __restrict__ pxy, const float* __restrict__ pxz, const float* __restrict__ pyz,
    const float* __restrict__ vx, const float* __restrict__ vy, const float* __restrict__ vz,
    const float* __restrict__ basis,
    __half* __restrict__ planesH, __half* __restrict__ linesH, float2* __restrict__ bpad,
    unsigned* __restrict__ hist) {
    const int bid = blockIdx.x;
    const int tid = threadIdx.x;
    if (bid < HIST_BLOCKS) {                // 4-point histogram into copy (bid&7)
        unsigned* h = hist + (size_t)(bid & 7) * NCELL;
        const int t = bid * BLK + tid;
        const float4* p4 = (const float4*)pts;
        const float4 f0 = p4[t*3+0], f1 = p4[t*3+1], f2 = p4[t*3+2];
        atomicAdd(&h[cell_key(f0.x, f0.y, f0.z)], 1u);
        atomicAdd(&h[cell_key(f0.w, f1.x, f1.y)], 1u);
        atomicAdd(&h[cell_key(f1.z, f1.w, f2.x)], 1u);
        atomicAdd(&h[cell_key(f2.y, f2.z, f2.w)], 1u);
    } else if (bid < HIST_BLOCKS + PLANE_BLOCKS) {   // planes -> fp16 channel-last
        const int pb = bid - HIST_BLOCKS;
        const int plane = pb / 400;
        const int texel = (pb % 400) * BLK + tid;
        const float* src = (plane == 0) ? pxy : (plane == 1 ? pxz : pyz);
        union { ushort u[16]; uint4 q[2]; } pk;
        #pragma unroll
        for (int c = 0; c < CCH; ++c)
            pk.u[c] = __half_as_ushort(__float2half(src[(size_t)c * HW + texel]));
        uint4* dst = (uint4*)(planesH + ((size_t)plane * HW + texel) * CCH);
        dst[0] = pk.q[0]; dst[1] = pk.q[1];
    } else if (bid < HIST_BLOCKS + PLANE_BLOCKS + LINE_BLOCKS) {  // lines
        const int idx = (bid - HIST_BLOCKS - PLANE_BLOCKS) * BLK + tid;
        if (idx >= 3 * RES) return;
        const int axis = idx / RES, t = idx % RES;
        const float* src = (axis == 0) ? vx : (axis == 1 ? vy : vz);
        union { ushort u[16]; uint4 q[2]; } pk;
        #pragma unroll
        for (int c = 0; c < CCH; ++c)
            pk.u[c] = __half_as_ushort(__float2half(src[c * RES + t]));
        uint4* dst = (uint4*)(linesH + ((size_t)axis * RES + t) * CCH);
        dst[0] = pk.q[0]; dst[1] = pk.q[1];
    } else {                                // basis (48,27) -> padded float2 (48,14)
        for (int k = tid; k < 48 * 14; k += BLK) {
            const int r = k / 14, f = k % 14;
            float x = basis[r * FD + 2 * f];
            float y = (2 * f + 1 < FD) ? basis[r * FD + 2 * f + 1] : 0.f;
            bpad[k] = make_float2(x, y);
        }
    }
}

// ---------------- scan: global exclusive scan over (cell, copy) -> per-copy cursors ----------------
__global__ __launch_bounds__(1024) void scan_kernel(const unsigned* __restrict__ hist,
                                                    unsigned* __restrict__ cursor) {
    __shared__ unsigned lsum[1024];
    const int t = threadIdx.x;
    const int base = t * 32;                 // 32 cells per thread
    // per-cell totals over the 8 copies, with running local sum
    unsigned tot[32];
    unsigned run = 0;
    #pragma unroll
    for (int q = 0; q < 8; ++q) {            // 8 uint4 = 32 cells, per copy below
        tot[4*q+0] = 0; tot[4*q+1] = 0; tot[4*q+2] = 0; tot[4*q+3] = 0;
    }
    #pragma unroll
    for (int k = 0; k < NHIST; ++k) {
        const uint4* h4 = (const uint4*)(hist + (size_t)k * NCELL + base);
        #pragma unroll
        for (int q = 0; q < 8; ++q) {
            uint4 v = h4[q];
            tot[4*q+0] += v.x; tot[4*q+1] += v.y; tot[4*q+2] += v.z; tot[4*q+3] += v.w;
        }
    }
    unsigned local[32];
    #pragma unroll
    for (int c = 0; c < 32; ++c) { local[c] = run; run += tot[c]; }
    lsum[t] = run;
    __syncthreads();
    for (int o = 1; o < 1024; o <<= 1) {
        unsigned v = (t >= o) ? lsum[t - o] : 0u;
        __syncthreads();
        lsum[t] += v;
        __syncthreads();
    }
    const unsigned b = lsum[t] - run;        // exclusive base of this thread's 32-cell chunk
    // per-copy cursor: cursor[k][c] = cellbase[c] + sum_{k'<k} hist[k'][c]
    unsigned cur[32];
    #pragma unroll
    for (int c = 0; c < 32; ++c) cur[c] = b + local[c];
    for (int k = 0; k < NHIST; ++k) {
        const uint4* h4 = (const uint4*)(hist + (size_t)k * NCELL + base);
        uint4* c4 = (uint4*)(cursor + (size_t)k * NCELL + base);
        #pragma unroll
        for (int q = 0; q < 8; ++q) {
            uint4 v = h4[q];
            c4[q] = make_uint4(cur[4*q+0], cur[4*q+1], cur[4*q+2], cur[4*q+3]);
            cur[4*q+0] += v.x; cur[4*q+1] += v.y; cur[4*q+2] += v.z; cur[4*q+3] += v.w;
        }
    }
}

// ---------------- scatter (4 pts/thread, XCD-local cursor copy) ----------------
__global__ __launch_bounds__(BLK) void scatter_kernel(const float* __restrict__ pts,
                                                      unsigned* __restrict__ cursor,
                                                      float4* __restrict__ sorted) {
    const int bid = blockIdx.x;
    unsigned* cur = cursor + (size_t)(bid & 7) * NCELL;
    const int t = bid * BLK + threadIdx.x;
    const float4* p4 = (const float4*)pts;
    const float4 f0 = p4[t*3+0], f1 = p4[t*3+1], f2 = p4[t*3+2];
    const int i0 = 4 * t;
    const unsigned pos0 = atomicAdd(&cur[cell_key(f0.x, f0.y, f0.z)], 1u);
    const unsigned pos1 = atomicAdd(&cur[cell_key(f0.w, f1.x, f1.y)], 1u);
    const unsigned pos2 = atomicAdd(&cur[cell_key(f1.z, f1.w, f2.x)], 1u);
    const unsigned pos3 = atomicAdd(&cur[cell_key(f2.y, f2.z, f2.w)], 1u);
    sorted[pos0] = make_float4(f0.x, f0.y, f0.z, __int_as_float(i0 + 0));
    sorted[pos1] = make_float4(f0.w, f1.x, f1.y, __int_as_float(i0 + 1));
    sorted[pos2] = make_float4(f1.z, f1.w, f2.x, __int_as_float(i0 + 2));
    sorted[pos3] = make_float4(f2.y, f2.z, f2.w, __int_as_float(i0 + 3));
}

// ---------------- eval ----------------
__device__ __forceinline__ void do_half(const uint4* __restrict__ P, const uint4* __restrict__ L,
                                        int t00, int t01, int t10, int t11, int l0, int l1,
                                        float wc, float wr, float lw, int h, int rbase,
                                        const float2* __restrict__ bp, float2 acc[14]) {
    const uint4 c00 = P[2*t00 + h], c01 = P[2*t01 + h];
    const uint4 c10 = P[2*t10 + h], c11 = P[2*t11 + h];
    const uint4 la4 = L[2*l0 + h],  lb4 = L[2*l1 + h];
    const float w00 = (1.f - wc) * (1.f - wr), w01 = wc * (1.f - wr);
    const float w10 = (1.f - wc) * wr,         w11 = wc * wr;
    const float2 w00_2 = make_float2(w00, w00), w01_2 = make_float2(w01, w01);
    const float2 w10_2 = make_float2(w10, w10), w11_2 = make_float2(w11, w11);
    const float2 lw2   = make_float2(lw, lw),   mlw2  = make_float2(1.f - lw, 1.f - lw);
    #pragma unroll
    for (int j = 0; j < 4; ++j) {
        const float2 v00 = h2f(lane_of(c00, j)), v01 = h2f(lane_of(c01, j));
        const float2 v10 = h2f(lane_of(c10, j)), v11 = h2f(lane_of(c11, j));
        float2 s = pk_mul(v00, w00_2);
        s = pk_fma(v01, w01_2, s);
        s = pk_fma(v10, w10_2, s);
        s = pk_fma(v11, w11_2, s);
        const float2 la = h2f(lane_of(la4, j)), lb = h2f(lane_of(lb4, j));
        float2 l = pk_mul(la, mlw2);
        l = pk_fma(lb, lw2, l);
        s = pk_mul(s, l);
        const int r0 = rbase + 8 * h + 2 * j;
        const float2 fx2 = make_float2(s.x, s.x);
        #pragma unroll
        for (int f = 0; f < 14; ++f) pk_fma_s(acc[f], fx2, bp[r0 * 14 + f]);
        const float2 fy2 = make_float2(s.y, s.y);
        #pragma unroll
        for (int f = 0; f < 14; ++f) pk_fma_s(acc[f], fy2, bp[(r0 + 1) * 14 + f]);
    }
}

__global__ __launch_bounds__(BLK, 6) void eval_kernel(
    const float4* __restrict__ sorted,
    const __half* __restrict__ planesH,
    const __half* __restrict__ linesH,
    const float2* __restrict__ bp,
    float* __restrict__ out) {
    constexpr int NBLK = NPTS / BLK;            // 8192
    constexpr int CHUNK = NBLK / 8;             // 1024
    const int bid = blockIdx.x;
    const int swz = (bid & 7) * CHUNK + (bid >> 3);   // contiguous sorted range per XCD
    const int j = swz * BLK + threadIdx.x;

    const float4 pt = sorted[j];
    const float px = pt.x, py = pt.y, pz = pt.z;
    const long long oi = (long long)__float_as_int(pt.w);

    const float scl = 0.5f * (RES - 1);
    const float fx = (px + 1.f) * scl, fy = (py + 1.f) * scl, fz = (pz + 1.f) * scl;
    const float xf = floorf(fx), yf = floorf(fy), zf = floorf(fz);
    const float wx = fx - xf, wy = fy - yf, wz = fz - zf;
    int x0 = min(max((int)xf, 0), RES - 1);
    int y0 = min(max((int)yf, 0), RES - 1);
    int z0 = min(max((int)zf, 0), RES - 1);
    const int x1 = min(x0 + 1, RES - 1);
    const int y1 = min(y0 + 1, RES - 1);
    const int z1 = min(z0 + 1, RES - 1);

    const uint4* Pxy = (const uint4*)planesH;
    const uint4* Pxz = (const uint4*)(planesH + (size_t)HW * CCH);
    const uint4* Pyz = (const uint4*)(planesH + (size_t)2 * HW * CCH);
    const uint4* Lx = (const uint4*)linesH;
    const uint4* Ly = (const uint4*)(linesH + (size_t)RES * CCH);
    const uint4* Lz = (const uint4*)(linesH + (size_t)2 * RES * CCH);

    float2 acc[14];
    #pragma unroll
    for (int f = 0; f < 14; ++f) acc[f] = make_float2(0.f, 0.f);

    do_half(Pxy, Lz, y0*RES+x0, y0*RES+x1, y1*RES+x0, y1*RES+x1, z0, z1, wx, wy, wz, 0,  0, bp, acc);
    do_half(Pxy, Lz, y0*RES+x0, y0*RES+x1, y1*RES+x0, y1*RES+x1, z0, z1, wx, wy, wz, 1,  0, bp, acc);
    do_half(Pxz, Ly, z0*RES+x0, z0*RES+x1, z1*RES+x0, z1*RES+x1, y0, y1, wx, wz, wy, 0, 16, bp, acc);
    do_half(Pxz, Ly, z0*RES+x0, z0*RES+x1, z1*RES+x0, z1*RES+x1, y0, y1, wx, wz, wy, 1, 16, bp, acc);
    do_half(Pyz, Lx, z0*RES+y0, z0*RES+y1, z1*RES+y0, z1*RES+y1, x0, x1, wy, wz, wx, 0, 32, bp, acc);
    do_half(Pyz, Lx, z0*RES+y0, z0*RES+y1, z1*RES+y0, z1*RES+y1, x0, x1, wy, wz, wx, 1, 32, bp, acc);

    float* op = out + oi * FD;
    #pragma unroll
    for (int f = 0; f < 14; ++f) {
        op[2*f] = acc[f].x;
        if (2*f + 1 < FD) op[2*f + 1] = acc[f].y;
    }
}

// ---------------- fallback (no workspace) ----------------
__device__ __forceinline__ float bilerp(const float* __restrict__ p,
                                        int o00, int o01, int o10, int o11,
                                        float wc, float wr) {
    float v00 = p[o00], v01 = p[o01], v10 = p[o10], v11 = p[o11];
    float top = v00 + wc * (v01 - v00);
    float bot = v10 + wc * (v11 - v10);
    return top + wr * (bot - top);
}

__global__ __launch_bounds__(BLK) void vm_eval_fallback(
    const float* __restrict__ pts,
    const float* __restrict__ pxy, const float* __restrict__ pyz, const float* __restrict__ pxz,
    const float* __restrict__ vx, const float* __restrict__ vy, const float* __restrict__ vz,
    const float* __restrict__ basis, float* __restrict__ out) {
    const long long i = (long long)blockIdx.x * BLK + threadIdx.x;
    const float px = pts[i*3], py = pts[i*3+1], pz = pts[i*3+2];
    const float scl = 0.5f * (RES - 1);
    const float fx = (px + 1.f) * scl, fy = (py + 1.f) * scl, fz = (pz + 1.f) * scl;
    const float xf = floorf(fx), yf = floorf(fy), zf = floorf(fz);
    const float wx = fx - xf, wy = fy - yf, wz = fz - zf;
    int x0 = min(max((int)xf, 0), RES - 1);
    int y0 = min(max((int)yf, 0), RES - 1);
    int z0 = min(max((int)zf, 0), RES - 1);
    const int x1 = min(x0+1, RES-1), y1 = min(y0+1, RES-1), z1 = min(z0+1, RES-1);
    float acc[FD];
    #pragma unroll
    for (int f = 0; f < FD; ++f) acc[f] = 0.f;
    #pragma unroll 4
    for (int c = 0; c < CCH; ++c) {
        const float* a = pxy + c * HW;
        const float* b = pxz + c * HW;
        const float* d = pyz + c * HW;
        float lz = vz[c*RES+z0]; lz += wz * (vz[c*RES+z1] - lz);
        float ly = vy[c*RES+y0]; ly += wy * (vy[c*RES+y1] - ly);
        float lx = vx[c*RES+x0]; lx += wx * (vx[c*RES+x1] - lx);
        const float fa = bilerp(a, y0*RES+x0, y0*RES+x1, y1*RES+x0, y1*RES+x1, wx, wy) * lz;
        const float fb = bilerp(b, z0*RES+x0, z0*RES+x1, z1*RES+x0, z1*RES+x1, wx, wz) * ly;
        const float fc = bilerp(d, z0*RES+y0, z0*RES+y1, z1*RES+y0, z1*RES+y1, wy, wz) * lx;
        #pragma unroll
        for (int f = 0; f < FD; ++f)
            acc[f] += fa * basis[c*FD+f] + fb * basis[(CCH+c)*FD+f] + fc * basis[(2*CCH+c)*FD+f];
    }
    float* op = out + i * FD;
    #pragma unroll
    for (int f = 0; f < FD; ++f) op[f] = acc[f];
}

extern "C" void kernel_launch(void* const* d_in, const int* in_sizes, int n_in,
                              void* d_out, int out_size, void* d_ws, size_t ws_size,
                              hipStream_t stream) {
    const float* pts   = (const float*)d_in[0];
    const float* pxy   = (const float*)d_in[1];
    const float* pyz   = (const float*)d_in[2];
    const float* pxz   = (const float*)d_in[3];
    const float* vx    = (const float*)d_in[4];
    const float* vy    = (const float*)d_in[5];
    const float* vz    = (const float*)d_in[6];
    const float* basis = (const float*)d_in[7];
    float* out = (float*)d_out;

    if (ws_size < WS_NEED) {
        vm_eval_fallback<<<NPTS / BLK, BLK, 0, stream>>>(pts, pxy, pyz, pxz, vx, vy, vz, basis, out);
        return;
    }

    uint8_t* w = (uint8_t*)d_ws;
    __half*   planesH = (__half*)(w + WS_PLANEH);
    __half*   linesH  = (__half*)(w + WS_LINEH);
    float2*   bpad    = (float2*)(w + WS_BPAD);
    unsigned* hist    = (unsigned*)(w + WS_HIST);
    unsigned* cursor  = (unsigned*)(w + WS_CURSOR);
    float4*   sorted  = (float4*)(w + WS_SORTED);

    hipMemsetAsync(hist, 0, (size_t)NHIST * NCELL * 4, stream);
    prep_kernel<<<HIST_BLOCKS + PLANE_BLOCKS + LINE_BLOCKS + 1, BLK, 0, stream>>>(
        pts, pxy, pxz, pyz, vx, vy, vz, basis, planesH, linesH, bpad, hist);
    scan_kernel<<<1, 1024, 0, stream>>>(hist, cursor);
    scatter_kernel<<<NPTS / (BLK * 4), BLK, 0, stream>>>(pts, cursor, sorted);
    eval_kernel<<<NPTS / BLK, BLK, 0, stream>>>(sorted, planesH, linesH, bpad, out);
}

// Round 7
// 411.987 us; speedup vs baseline: 2.4066x; 1.3372x over previous
//
#include <hip/hip_runtime.h>
#include <hip/hip_fp16.h>
#include <stdint.h>

// VM-factorized voxel grid: N pts -> 48 feats (3 planes x 16ch) -> 27 outputs.
// Pipeline: memset hist -> prep (planes/lines -> fp16 channel-last, basis pad,
// 4-pt/thread histogram) -> scan -> 4-pt/thread scatter -> eval
// (fp16 gathers, packed-f32 interp + matmul, LDS-staged COALESCED row stores).

constexpr int NPTS = 2097152;
constexpr int CCH  = 16;
constexpr int RES  = 320;
constexpr long long HW = (long long)RES * RES;   // 102400
constexpr int FD   = 27;
constexpr int BLK  = 256;
constexpr int NCELL = 32768;                     // 32^3 Morton cells

constexpr int HIST_BLOCKS = NPTS / (BLK * 4);    // 2048
constexpr int PLANE_BLOCKS = 1200;               // 3 * 400
constexpr int LINE_BLOCKS = 4;

// ---- workspace layout (bytes), all 16B-aligned ----
constexpr size_t WS_PLANEH = 0;                                   // 3*HW*16*2 = 9,830,400
constexpr size_t WS_LINEH  = WS_PLANEH + 3ull*HW*CCH*2;           // 30,720
constexpr size_t WS_BPAD   = WS_LINEH + 3ull*RES*CCH*2;           // 5,376
constexpr size_t WS_HIST   = WS_BPAD + 48ull*14*8;                // 131,072
constexpr size_t WS_CURSOR = WS_HIST + (size_t)NCELL*4;           // 131,072
constexpr size_t WS_SORTED = WS_CURSOR + (size_t)NCELL*4;         // N*16
constexpr size_t WS_NEED   = WS_SORTED + (size_t)NPTS*16;         // ~43.7 MB

// ---------------- helpers ----------------
__device__ __forceinline__ unsigned spread5(unsigned v) {
    return (v & 1u) | ((v & 2u) << 2) | ((v & 4u) << 4) | ((v & 8u) << 6) | ((v & 16u) << 8);
}
__device__ __forceinline__ int cell_key(float px, float py, float pz) {
    int cx = min(max((int)((px + 1.f) * 16.f), 0), 31);
    int cy = min(max((int)((py + 1.f) * 16.f), 0), 31);
    int cz = min(max((int)((pz + 1.f) * 16.f), 0), 31);
    return (int)(spread5((unsigned)cx) | (spread5((unsigned)cy) << 1) | (spread5((unsigned)cz) << 2));
}

// packed fp32 ops (VOP3P). b from SGPR pair for the basis (uniform), VGPR otherwise.
__device__ __forceinline__ void pk_fma_s(float2& acc, const float2 ab, const float2 b) {
    unsigned long long bs;
    __builtin_memcpy(&bs, &b, 8);
    asm("v_pk_fma_f32 %0, %1, %2, %0" : "+v"(acc) : "v"(ab), "s"(bs));
}
__device__ __forceinline__ float2 pk_mul(float2 a, float2 b) {
    float2 d; asm("v_pk_mul_f32 %0, %1, %2" : "=v"(d) : "v"(a), "v"(b)); return d;
}
__device__ __forceinline__ float2 pk_fma(float2 a, float2 b, float2 c) {
    float2 d; asm("v_pk_fma_f32 %0, %1, %2, %3" : "=v"(d) : "v"(a), "v"(b), "v"(c)); return d;
}

__device__ __forceinline__ float2 h2f(unsigned u) {
    __half2 h = *(__half2*)&u;
    return __half22float2(h);
}
__device__ __forceinline__ unsigned lane_of(uint4 q, int j) {
    return j == 0 ? q.x : (j == 1 ? q.y : (j == 2 ? q.z : q.w));
}

// ---------------- prep: hist (4 pts/thread) + planes/lines fp16 + basis pad ----------------
__global__ __launch_bounds__(BLK) void prep_kernel(
    const float* __restrict__ pts,
    const float* __restrict__ pxy, const float* __restrict__ pxz, const float* __restrict__ pyz,
    const float* __restrict__ vx, const float* __restrict__ vy, const float* __restrict__ vz,
    const float* __restrict__ basis,
    __half* __restrict__ planesH, __half* __restrict__ linesH, float2* __restrict__ bpad,
    unsigned* __restrict__ hist) {
    const int bid = blockIdx.x;
    const int tid = threadIdx.x;
    if (bid < HIST_BLOCKS) {                // 4-point histogram
        const int t = bid * BLK + tid;
        const float4* p4 = (const float4*)pts;
        const float4 f0 = p4[t*3+0], f1 = p4[t*3+1], f2 = p4[t*3+2];
        atomicAdd(&hist[cell_key(f0.x, f0.y, f0.z)], 1u);
        atomicAdd(&hist[cell_key(f0.w, f1.x, f1.y)], 1u);
        atomicAdd(&hist[cell_key(f1.z, f1.w, f2.x)], 1u);
        atomicAdd(&hist[cell_key(f2.y, f2.z, f2.w)], 1u);
    } else if (bid < HIST_BLOCKS + PLANE_BLOCKS) {   // planes -> fp16 channel-last
        const int pb = bid - HIST_BLOCKS;
        const int plane = pb / 400;
        const int texel = (pb % 400) * BLK + tid;
        const float* src = (plane == 0) ? pxy : (plane == 1 ? pxz : pyz);
        union { ushort u[16]; uint4 q[2]; } pk;
        #pragma unroll
        for (int c = 0; c < CCH; ++c)
            pk.u[c] = __half_as_ushort(__float2half(src[(size_t)c * HW + texel]));
        uint4* dst = (uint4*)(planesH + ((size_t)plane * HW + texel) * CCH);
        dst[0] = pk.q[0]; dst[1] = pk.q[1];
    } else if (bid < HIST_BLOCKS + PLANE_BLOCKS + LINE_BLOCKS) {  // lines
        const int idx = (bid - HIST_BLOCKS - PLANE_BLOCKS) * BLK + tid;
        if (idx >= 3 * RES) return;
        const int axis = idx / RES, t = idx % RES;
        const float* src = (axis == 0) ? vx : (axis == 1 ? vy : vz);
        union { ushort u[16]; uint4 q[2]; } pk;
        #pragma unroll
        for (int c = 0; c < CCH; ++c)
            pk.u[c] = __half_as_ushort(__float2half(src[c * RES + t]));
        uint4* dst = (uint4*)(linesH + ((size_t)axis * RES + t) * CCH);
        dst[0] = pk.q[0]; dst[1] = pk.q[1];
    } else {                                // basis (48,27) -> padded float2 (48,14)
        for (int k = tid; k < 48 * 14; k += BLK) {
            const int r = k / 14, f = k % 14;
            float x = basis[r * FD + 2 * f];
            float y = (2 * f + 1 < FD) ? basis[r * FD + 2 * f + 1] : 0.f;
            bpad[k] = make_float2(x, y);
        }
    }
}

// ---------------- scan ----------------
__global__ __launch_bounds__(1024) void scan_kernel(const unsigned* __restrict__ hist,
                                                    unsigned* __restrict__ cursor) {
    __shared__ unsigned lsum[1024];
    const int t = threadIdx.x;
    const int base = t * 32;
    const uint4* h4 = (const uint4*)(hist + base);
    unsigned local[32];
    unsigned run = 0;
    #pragma unroll
    for (int q = 0; q < 8; ++q) {
        uint4 v = h4[q];
        local[4*q+0] = run; run += v.x;
        local[4*q+1] = run; run += v.y;
        local[4*q+2] = run; run += v.z;
        local[4*q+3] = run; run += v.w;
    }
    lsum[t] = run;
    __syncthreads();
    for (int o = 1; o < 1024; o <<= 1) {
        unsigned v = (t >= o) ? lsum[t - o] : 0u;
        __syncthreads();
        lsum[t] += v;
        __syncthreads();
    }
    const unsigned b = lsum[t] - run;
    uint4* c4 = (uint4*)(cursor + base);
    #pragma unroll
    for (int q = 0; q < 8; ++q)
        c4[q] = make_uint4(b + local[4*q+0], b + local[4*q+1], b + local[4*q+2], b + local[4*q+3]);
}

// ---------------- scatter (4 pts/thread) ----------------
__global__ __launch_bounds__(BLK) void scatter_kernel(const float* __restrict__ pts,
                                                      unsigned* __restrict__ cursor,
                                                      float4* __restrict__ sorted) {
    const int t = blockIdx.x * BLK + threadIdx.x;
    const float4* p4 = (const float4*)pts;
    const float4 f0 = p4[t*3+0], f1 = p4[t*3+1], f2 = p4[t*3+2];
    const int i0 = 4 * t;
    const unsigned pos0 = atomicAdd(&cursor[cell_key(f0.x, f0.y, f0.z)], 1u);
    const unsigned pos1 = atomicAdd(&cursor[cell_key(f0.w, f1.x, f1.y)], 1u);
    const unsigned pos2 = atomicAdd(&cursor[cell_key(f1.z, f1.w, f2.x)], 1u);
    const unsigned pos3 = atomicAdd(&cursor[cell_key(f2.y, f2.z, f2.w)], 1u);
    sorted[pos0] = make_float4(f0.x, f0.y, f0.z, __int_as_float(i0 + 0));
    sorted[pos1] = make_float4(f0.w, f1.x, f1.y, __int_as_float(i0 + 1));
    sorted[pos2] = make_float4(f1.z, f1.w, f2.x, __int_as_float(i0 + 2));
    sorted[pos3] = make_float4(f2.y, f2.z, f2.w, __int_as_float(i0 + 3));
}

// ---------------- eval ----------------
__device__ __forceinline__ void do_half(const uint4* __restrict__ P, const uint4* __restrict__ L,
                                        int t00, int t01, int t10, int t11, int l0, int l1,
                                        float wc, float wr, float lw, int h, int rbase,
                                        const float2* __restrict__ bp, float2 acc[14]) {
    const uint4 c00 = P[2*t00 + h], c01 = P[2*t01 + h];
    const uint4 c10 = P[2*t10 + h], c11 = P[2*t11 + h];
    const uint4 la4 = L[2*l0 + h],  lb4 = L[2*l1 + h];
    const float w00 = (1.f - wc) * (1.f - wr), w01 = wc * (1.f - wr);
    const float w10 = (1.f - wc) * wr,         w11 = wc * wr;
    const float2 w00_2 = make_float2(w00, w00), w01_2 = make_float2(w01, w01);
    const float2 w10_2 = make_float2(w10, w10), w11_2 = make_float2(w11, w11);
    const float2 lw2   = make_float2(lw, lw),   mlw2  = make_float2(1.f - lw, 1.f - lw);
    #pragma unroll
    for (int j = 0; j < 4; ++j) {
        const float2 v00 = h2f(lane_of(c00, j)), v01 = h2f(lane_of(c01, j));
        const float2 v10 = h2f(lane_of(c10, j)), v11 = h2f(lane_of(c11, j));
        float2 s = pk_mul(v00, w00_2);
        s = pk_fma(v01, w01_2, s);
        s = pk_fma(v10, w10_2, s);
        s = pk_fma(v11, w11_2, s);
        const float2 la = h2f(lane_of(la4, j)), lb = h2f(lane_of(lb4, j));
        float2 l = pk_mul(la, mlw2);
        l = pk_fma(lb, lw2, l);
        s = pk_mul(s, l);
        const int r0 = rbase + 8 * h + 2 * j;
        const float2 fx2 = make_float2(s.x, s.x);
        #pragma unroll
        for (int f = 0; f < 14; ++f) pk_fma_s(acc[f], fx2, bp[r0 * 14 + f]);
        const float2 fy2 = make_float2(s.y, s.y);
        #pragma unroll
        for (int f = 0; f < 14; ++f) pk_fma_s(acc[f], fy2, bp[(r0 + 1) * 14 + f]);
    }
}

__global__ __launch_bounds__(BLK, 5) void eval_kernel(
    const float4* __restrict__ sorted,
    const __half* __restrict__ planesH,
    const __half* __restrict__ linesH,
    const float2* __restrict__ bp,
    float* __restrict__ out) {
    __shared__ float s_out[BLK * FD];   // 27648 B
    __shared__ int   s_oi[BLK];         // 1024 B
    constexpr int NBLK = NPTS / BLK;            // 8192
    constexpr int CHUNK = NBLK / 8;             // 1024
    const int bid = blockIdx.x;
    const int tid = threadIdx.x;
    const int swz = (bid & 7) * CHUNK + (bid >> 3);   // contiguous sorted range per XCD
    const int j = swz * BLK + tid;

    const float4 pt = sorted[j];
    const float px = pt.x, py = pt.y, pz = pt.z;
    const int oi = __float_as_int(pt.w);

    const float scl = 0.5f * (RES - 1);
    const float fx = (px + 1.f) * scl, fy = (py + 1.f) * scl, fz = (pz + 1.f) * scl;
    const float xf = floorf(fx), yf = floorf(fy), zf = floorf(fz);
    const float wx = fx - xf, wy = fy - yf, wz = fz - zf;
    int x0 = min(max((int)xf, 0), RES - 1);
    int y0 = min(max((int)yf, 0), RES - 1);
    int z0 = min(max((int)zf, 0), RES - 1);
    const int x1 = min(x0 + 1, RES - 1);
    const int y1 = min(y0 + 1, RES - 1);
    const int z1 = min(z0 + 1, RES - 1);

    const uint4* Pxy = (const uint4*)planesH;
    const uint4* Pxz = (const uint4*)(planesH + (size_t)HW * CCH);
    const uint4* Pyz = (const uint4*)(planesH + (size_t)2 * HW * CCH);
    const uint4* Lx = (const uint4*)linesH;
    const uint4* Ly = (const uint4*)(linesH + (size_t)RES * CCH);
    const uint4* Lz = (const uint4*)(linesH + (size_t)2 * RES * CCH);

    float2 acc[14];
    #pragma unroll
    for (int f = 0; f < 14; ++f) acc[f] = make_float2(0.f, 0.f);

    do_half(Pxy, Lz, y0*RES+x0, y0*RES+x1, y1*RES+x0, y1*RES+x1, z0, z1, wx, wy, wz, 0,  0, bp, acc);
    do_half(Pxy, Lz, y0*RES+x0, y0*RES+x1, y1*RES+x0, y1*RES+x1, z0, z1, wx, wy, wz, 1,  0, bp, acc);
    do_half(Pxz, Ly, z0*RES+x0, z0*RES+x1, z1*RES+x0, z1*RES+x1, y0, y1, wx, wz, wy, 0, 16, bp, acc);
    do_half(Pxz, Ly, z0*RES+x0, z0*RES+x1, z1*RES+x0, z1*RES+x1, y0, y1, wx, wz, wy, 1, 16, bp, acc);
    do_half(Pyz, Lx, z0*RES+y0, z0*RES+y1, z1*RES+y0, z1*RES+y1, x0, x1, wy, wz, wx, 0, 32, bp, acc);
    do_half(Pyz, Lx, z0*RES+y0, z0*RES+y1, z1*RES+y0, z1*RES+y1, x0, x1, wy, wz, wx, 1, 32, bp, acc);

    // stage results + original indices in LDS
    const int sbase = tid * FD;
    #pragma unroll
    for (int f = 0; f < 14; ++f) {
        s_out[sbase + 2*f] = acc[f].x;
        if (2*f + 1 < FD) s_out[sbase + 2*f + 1] = acc[f].y;
    }
    s_oi[tid] = oi;
    __syncthreads();

    // coalesced row stores: each wave writes 64 of the block's points,
    // 2 points per store instruction (lanes 0-26 -> point p, lanes 32-58 -> p+1).
    const int wid  = tid >> 6;
    const int lane = tid & 63;
    const int sub  = lane >> 5;       // which point of the pair
    const int col  = lane & 31;       // dword within the 27-dword row
    if (col < FD) {
        #pragma unroll
        for (int it = 0; it < 32; ++it) {
            const int p = wid * 64 + it * 2 + sub;
            const int o = s_oi[p];
            out[(size_t)o * FD + col] = s_out[p * FD + col];
        }
    }
}

// ---------------- fallback (no workspace) ----------------
__device__ __forceinline__ float bilerp(const float* __restrict__ p,
                                        int o00, int o01, int o10, int o11,
                                        float wc, float wr) {
    float v00 = p[o00], v01 = p[o01], v10 = p[o10], v11 = p[o11];
    float top = v00 + wc * (v01 - v00);
    float bot = v10 + wc * (v11 - v10);
    return top + wr * (bot - top);
}

__global__ __launch_bounds__(BLK) void vm_eval_fallback(
    const float* __restrict__ pts,
    const float* __restrict__ pxy, const float* __restrict__ pyz, const float* __restrict__ pxz,
    const float* __restrict__ vx, const float* __restrict__ vy, const float* __restrict__ vz,
    const float* __restrict__ basis, float* __restrict__ out) {
    const long long i = (long long)blockIdx.x * BLK + threadIdx.x;
    const float px = pts[i*3], py = pts[i*3+1], pz = pts[i*3+2];
    const float scl = 0.5f * (RES - 1);
    const float fx = (px + 1.f) * scl, fy = (py + 1.f) * scl, fz = (pz + 1.f) * scl;
    const float xf = floorf(fx), yf = floorf(fy), zf = floorf(fz);
    const float wx = fx - xf, wy = fy - yf, wz = fz - zf;
    int x0 = min(max((int)xf, 0), RES - 1);
    int y0 = min(max((int)yf, 0), RES - 1);
    int z0 = min(max((int)zf, 0), RES - 1);
    const int x1 = min(x0+1, RES-1), y1 = min(y0+1, RES-1), z1 = min(z0+1, RES-1);
    float acc[FD];
    #pragma unroll
    for (int f = 0; f < FD; ++f) acc[f] = 0.f;
    #pragma unroll 4
    for (int c = 0; c < CCH; ++c) {
        const float* a = pxy + c * HW;
        const float* b = pxz + c * HW;
        const float* d = pyz + c * HW;
        float lz = vz[c*RES+z0]; lz += wz * (vz[c*RES+z1] - lz);
        float ly = vy[c*RES+y0]; ly += wy * (vy[c*RES+y1] - ly);
        float lx = vx[c*RES+x0]; lx += wx * (vx[c*RES+x1] - lx);
        const float fa = bilerp(a, y0*RES+x0, y0*RES+x1, y1*RES+x0, y1*RES+x1, wx, wy) * lz;
        const float fb = bilerp(b, z0*RES+x0, z0*RES+x1, z1*RES+x0, z1*RES+x1, wx, wz) * ly;
        const float fc = bilerp(d, z0*RES+y0, z0*RES+y1, z1*RES+y0, z1*RES+y1, wy, wz) * lx;
        #pragma unroll
        for (int f = 0; f < FD; ++f)
            acc[f] += fa * basis[c*FD+f] + fb * basis[(CCH+c)*FD+f] + fc * basis[(2*CCH+c)*FD+f];
    }
    float* op = out + i * FD;
    #pragma unroll
    for (int f = 0; f < FD; ++f) op[f] = acc[f];
}

extern "C" void kernel_launch(void* const* d_in, const int* in_sizes, int n_in,
                              void* d_out, int out_size, void* d_ws, size_t ws_size,
                              hipStream_t stream) {
    const float* pts   = (const float*)d_in[0];
    const float* pxy   = (const float*)d_in[1];
    const float* pyz   = (const float*)d_in[2];
    const float* pxz   = (const float*)d_in[3];
    const float* vx    = (const float*)d_in[4];
    const float* vy    = (const float*)d_in[5];
    const float* vz    = (const float*)d_in[6];
    const float* basis = (const float*)d_in[7];
    float* out = (float*)d_out;

    if (ws_size < WS_NEED) {
        vm_eval_fallback<<<NPTS / BLK, BLK, 0, stream>>>(pts, pxy, pyz, pxz, vx, vy, vz, basis, out);
        return;
    }

    uint8_t* w = (uint8_t*)d_ws;
    __half*   planesH = (__half*)(w + WS_PLANEH);
    __half*   linesH  = (__half*)(w + WS_LINEH);
    float2*   bpad    = (float2*)(w + WS_BPAD);
    unsigned* hist    = (unsigned*)(w + WS_HIST);
    unsigned* cursor  = (unsigned*)(w + WS_CURSOR);
    float4*   sorted  = (float4*)(w + WS_SORTED);

    hipMemsetAsync(hist, 0, (size_t)NCELL * 4, stream);
    prep_kernel<<<HIST_BLOCKS + PLANE_BLOCKS + LINE_BLOCKS + 1, BLK, 0, stream>>>(
        pts, pxy, pxz, pyz, vx, vy, vz, basis, planesH, linesH, bpad, hist);
    scan_kernel<<<1, 1024, 0, stream>>>(hist, cursor);
    scatter_kernel<<<NPTS / (BLK * 4), BLK, 0, stream>>>(pts, cursor, sorted);
    eval_kernel<<<NPTS / BLK, BLK, 0, stream>>>(sorted, planesH, linesH, bpad, out);
}

// Round 8
// 226.596 us; speedup vs baseline: 4.3756x; 1.8182x over previous
//
#include <hip/hip_runtime.h>
#include <hip/hip_fp16.h>
#include <stdint.h>

// VM-factorized voxel grid: N pts -> 48 feats (3 planes x 16ch) -> 27 outputs.
// Pipeline: memset coarse-hist(512) -> prep (planes/lines -> fp16 channel-last,
// basis pad, coarse hist via LDS + 1 global atomic per (block,cell)) -> scan(512)
// -> scatter (LDS rank, block-contiguous runs, coalesced-ish stores) -> eval
// (fp16 gathers, packed-f32 interp + matmul, LDS-staged coalesced row stores).

constexpr int NPTS = 2097152;
constexpr int CCH  = 16;
constexpr int RES  = 320;
constexpr long long HW = (long long)RES * RES;   // 102400
constexpr int FD   = 27;
constexpr int BLK  = 256;
constexpr int NCELL = 512;                       // 8^3 coarse Morton cells
constexpr int PTS_PER_SORTBLK = 4096;            // 256 thr x 16 pts

constexpr int HIST_BLOCKS = NPTS / PTS_PER_SORTBLK;   // 512
constexpr int PLANE_BLOCKS = 1200;               // 3 * 400
constexpr int LINE_BLOCKS = 4;

// ---- workspace layout (bytes), all 16B-aligned ----
constexpr size_t WS_PLANEH = 0;                                   // 3*HW*16*2 = 9,830,400
constexpr size_t WS_LINEH  = WS_PLANEH + 3ull*HW*CCH*2;           // 30,720
constexpr size_t WS_BPAD   = WS_LINEH + 3ull*RES*CCH*2;           // 5,376
constexpr size_t WS_CHIST  = WS_BPAD + 48ull*14*8;                // 2,048
constexpr size_t WS_CURSOR = WS_CHIST + (size_t)NCELL*4;          // 2,048
constexpr size_t WS_SORTED = WS_CURSOR + (size_t)NCELL*4;         // N*16
constexpr size_t WS_NEED   = WS_SORTED + (size_t)NPTS*16;         // ~43.4 MB

// ---------------- helpers ----------------
__device__ __forceinline__ unsigned spread3(unsigned v) {
    // 3 bits -> bits {0,3,6}
    return (v & 1u) | ((v & 2u) << 2) | ((v & 4u) << 4);
}
__device__ __forceinline__ int cell_key8(float px, float py, float pz) {
    int cx = min(max((int)((px + 1.f) * 4.f), 0), 7);
    int cy = min(max((int)((py + 1.f) * 4.f), 0), 7);
    int cz = min(max((int)((pz + 1.f) * 4.f), 0), 7);
    return (int)(spread3((unsigned)cx) | (spread3((unsigned)cy) << 1) | (spread3((unsigned)cz) << 2));
}

// packed fp32 ops (VOP3P). b from SGPR pair for the basis (uniform), VGPR otherwise.
__device__ __forceinline__ void pk_fma_s(float2& acc, const float2 ab, const float2 b) {
    unsigned long long bs;
    __builtin_memcpy(&bs, &b, 8);
    asm("v_pk_fma_f32 %0, %1, %2, %0" : "+v"(acc) : "v"(ab), "s"(bs));
}
__device__ __forceinline__ float2 pk_mul(float2 a, float2 b) {
    float2 d; asm("v_pk_mul_f32 %0, %1, %2" : "=v"(d) : "v"(a), "v"(b)); return d;
}
__device__ __forceinline__ float2 pk_fma(float2 a, float2 b, float2 c) {
    float2 d; asm("v_pk_fma_f32 %0, %1, %2, %3" : "=v"(d) : "v"(a), "v"(b), "v"(c)); return d;
}

__device__ __forceinline__ float2 h2f(unsigned u) {
    __half2 h = *(__half2*)&u;
    return __half22float2(h);
}
__device__ __forceinline__ unsigned lane_of(uint4 q, int j) {
    return j == 0 ? q.x : (j == 1 ? q.y : (j == 2 ? q.z : q.w));
}

// ---------------- prep: coarse hist (16 pts/thread, LDS) + planes/lines fp16 + basis pad ----------------
__global__ __launch_bounds__(BLK) void prep_kernel(
    const float* __restrict__ pts,
    const float* __restrict__ pxy, const float* __restrict__ pxz, const float* __restrict__ pyz,
    const float* __restrict__ vx, const float* __restrict__ vy, const float* __restrict__ vz,
    const float* __restrict__ basis,
    __half* __restrict__ planesH, __half* __restrict__ linesH, float2* __restrict__ bpad,
    unsigned* __restrict__ chist) {
    __shared__ unsigned lh[NCELL];
    const int bid = blockIdx.x;
    const int tid = threadIdx.x;
    if (bid < HIST_BLOCKS) {                // coarse histogram, 4096 pts/block
        lh[tid] = 0u; lh[tid + 256] = 0u;
        __syncthreads();
        const float4* p4 = ((const float4*)pts) + (size_t)bid * 3072;
        #pragma unroll
        for (int g = 0; g < 4; ++g) {
            const float4 a = p4[tid*12 + g*3 + 0];
            const float4 b = p4[tid*12 + g*3 + 1];
            const float4 c = p4[tid*12 + g*3 + 2];
            atomicAdd(&lh[cell_key8(a.x, a.y, a.z)], 1u);
            atomicAdd(&lh[cell_key8(a.w, b.x, b.y)], 1u);
            atomicAdd(&lh[cell_key8(b.z, b.w, c.x)], 1u);
            atomicAdd(&lh[cell_key8(c.y, c.z, c.w)], 1u);
        }
        __syncthreads();
        if (lh[tid])       atomicAdd(&chist[tid],       lh[tid]);
        if (lh[tid + 256]) atomicAdd(&chist[tid + 256], lh[tid + 256]);
    } else if (bid < HIST_BLOCKS + PLANE_BLOCKS) {   // planes -> fp16 channel-last
        const int pb = bid - HIST_BLOCKS;
        const int plane = pb / 400;
        const int texel = (pb % 400) * BLK + tid;
        const float* src = (plane == 0) ? pxy : (plane == 1 ? pxz : pyz);
        union { ushort u[16]; uint4 q[2]; } pk;
        #pragma unroll
        for (int c = 0; c < CCH; ++c)
            pk.u[c] = __half_as_ushort(__float2half(src[(size_t)c * HW + texel]));
        uint4* dst = (uint4*)(planesH + ((size_t)plane * HW + texel) * CCH);
        dst[0] = pk.q[0]; dst[1] = pk.q[1];
    } else if (bid < HIST_BLOCKS + PLANE_BLOCKS + LINE_BLOCKS) {  // lines
        const int idx = (bid - HIST_BLOCKS - PLANE_BLOCKS) * BLK + tid;
        if (idx >= 3 * RES) return;
        const int axis = idx / RES, t = idx % RES;
        const float* src = (axis == 0) ? vx : (axis == 1 ? vy : vz);
        union { ushort u[16]; uint4 q[2]; } pk;
        #pragma unroll
        for (int c = 0; c < CCH; ++c)
            pk.u[c] = __half_as_ushort(__float2half(src[c * RES + t]));
        uint4* dst = (uint4*)(linesH + ((size_t)axis * RES + t) * CCH);
        dst[0] = pk.q[0]; dst[1] = pk.q[1];
    } else {                                // basis (48,27) -> padded float2 (48,14)
        for (int k = tid; k < 48 * 14; k += BLK) {
            const int r = k / 14, f = k % 14;
            float x = basis[r * FD + 2 * f];
            float y = (2 * f + 1 < FD) ? basis[r * FD + 2 * f + 1] : 0.f;
            bpad[k] = make_float2(x, y);
        }
    }
}

// ---------------- scan: exclusive scan of 512 coarse-cell counts -> cursor ----------------
__global__ __launch_bounds__(NCELL) void scan_kernel(const unsigned* __restrict__ chist,
                                                     unsigned* __restrict__ cursor) {
    __shared__ unsigned l[NCELL];
    const int t = threadIdx.x;
    const unsigned v = chist[t];
    l[t] = v;
    __syncthreads();
    for (int o = 1; o < NCELL; o <<= 1) {
        unsigned u = (t >= o) ? l[t - o] : 0u;
        __syncthreads();
        l[t] += u;
        __syncthreads();
    }
    cursor[t] = l[t] - v;   // exclusive
}

// ---------------- scatter: LDS rank + 1 global atomic per (block,cell) ----------------
__global__ __launch_bounds__(BLK) void scatter_kernel(const float* __restrict__ pts,
                                                      unsigned* __restrict__ cursor,
                                                      float4* __restrict__ sorted) {
    __shared__ unsigned lh[NCELL];
    __shared__ unsigned lb[NCELL];
    const int bid = blockIdx.x;
    const int tid = threadIdx.x;
    lh[tid] = 0u; lh[tid + 256] = 0u;
    __syncthreads();
    const float4* p4 = ((const float4*)pts) + (size_t)bid * 3072;
    unsigned kr[16];   // (key<<16) | rank   (rank < 4096)
    #pragma unroll
    for (int g = 0; g < 4; ++g) {
        const float4 a = p4[tid*12 + g*3 + 0];
        const float4 b = p4[tid*12 + g*3 + 1];
        const float4 c = p4[tid*12 + g*3 + 2];
        int k; unsigned r;
        k = cell_key8(a.x, a.y, a.z); r = atomicAdd(&lh[k], 1u); kr[g*4+0] = ((unsigned)k << 16) | r;
        k = cell_key8(a.w, b.x, b.y); r = atomicAdd(&lh[k], 1u); kr[g*4+1] = ((unsigned)k << 16) | r;
        k = cell_key8(b.z, b.w, c.x); r = atomicAdd(&lh[k], 1u); kr[g*4+2] = ((unsigned)k << 16) | r;
        k = cell_key8(c.y, c.z, c.w); r = atomicAdd(&lh[k], 1u); kr[g*4+3] = ((unsigned)k << 16) | r;
    }
    __syncthreads();
    lb[tid]       = atomicAdd(&cursor[tid],       lh[tid]);
    lb[tid + 256] = atomicAdd(&cursor[tid + 256], lh[tid + 256]);
    __syncthreads();
    const int ibase = bid * PTS_PER_SORTBLK + tid * 16;
    #pragma unroll
    for (int g = 0; g < 4; ++g) {
        const float4 a = p4[tid*12 + g*3 + 0];
        const float4 b = p4[tid*12 + g*3 + 1];
        const float4 c = p4[tid*12 + g*3 + 2];
        unsigned e;
        e = kr[g*4+0]; sorted[lb[e >> 16] + (e & 0xffffu)] = make_float4(a.x, a.y, a.z, __int_as_float(ibase + g*4 + 0));
        e = kr[g*4+1]; sorted[lb[e >> 16] + (e & 0xffffu)] = make_float4(a.w, b.x, b.y, __int_as_float(ibase + g*4 + 1));
        e = kr[g*4+2]; sorted[lb[e >> 16] + (e & 0xffffu)] = make_float4(b.z, b.w, c.x, __int_as_float(ibase + g*4 + 2));
        e = kr[g*4+3]; sorted[lb[e >> 16] + (e & 0xffffu)] = make_float4(c.y, c.z, c.w, __int_as_float(ibase + g*4 + 3));
    }
}

// ---------------- eval ----------------
__device__ __forceinline__ void do_half(const uint4* __restrict__ P, const uint4* __restrict__ L,
                                        int t00, int t01, int t10, int t11, int l0, int l1,
                                        float wc, float wr, float lw, int h, int rbase,
                                        const float2* __restrict__ bp, float2 acc[14]) {
    const uint4 c00 = P[2*t00 + h], c01 = P[2*t01 + h];
    const uint4 c10 = P[2*t10 + h], c11 = P[2*t11 + h];
    const uint4 la4 = L[2*l0 + h],  lb4 = L[2*l1 + h];
    const float w00 = (1.f - wc) * (1.f - wr), w01 = wc * (1.f - wr);
    const float w10 = (1.f - wc) * wr,         w11 = wc * wr;
    const float2 w00_2 = make_float2(w00, w00), w01_2 = make_float2(w01, w01);
    const float2 w10_2 = make_float2(w10, w10), w11_2 = make_float2(w11, w11);
    const float2 lw2   = make_float2(lw, lw),   mlw2  = make_float2(1.f - lw, 1.f - lw);
    #pragma unroll
    for (int j = 0; j < 4; ++j) {
        const float2 v00 = h2f(lane_of(c00, j)), v01 = h2f(lane_of(c01, j));
        const float2 v10 = h2f(lane_of(c10, j)), v11 = h2f(lane_of(c11, j));
        float2 s = pk_mul(v00, w00_2);
        s = pk_fma(v01, w01_2, s);
        s = pk_fma(v10, w10_2, s);
        s = pk_fma(v11, w11_2, s);
        const float2 la = h2f(lane_of(la4, j)), lb = h2f(lane_of(lb4, j));
        float2 l = pk_mul(la, mlw2);
        l = pk_fma(lb, lw2, l);
        s = pk_mul(s, l);
        const int r0 = rbase + 8 * h + 2 * j;
        const float2 fx2 = make_float2(s.x, s.x);
        #pragma unroll
        for (int f = 0; f < 14; ++f) pk_fma_s(acc[f], fx2, bp[r0 * 14 + f]);
        const float2 fy2 = make_float2(s.y, s.y);
        #pragma unroll
        for (int f = 0; f < 14; ++f) pk_fma_s(acc[f], fy2, bp[(r0 + 1) * 14 + f]);
    }
}

__global__ __launch_bounds__(BLK, 5) void eval_kernel(
    const float4* __restrict__ sorted,
    const __half* __restrict__ planesH,
    const __half* __restrict__ linesH,
    const float2* __restrict__ bp,
    float* __restrict__ out) {
    __shared__ float s_out[BLK * FD];   // 27648 B
    __shared__ int   s_oi[BLK];         // 1024 B
    constexpr int NBLK = NPTS / BLK;            // 8192
    constexpr int CHUNK = NBLK / 8;             // 1024
    const int bid = blockIdx.x;
    const int tid = threadIdx.x;
    const int swz = (bid & 7) * CHUNK + (bid >> 3);   // contiguous sorted range per XCD
    const int j = swz * BLK + tid;

    const float4 pt = sorted[j];
    const float px = pt.x, py = pt.y, pz = pt.z;
    const int oi = __float_as_int(pt.w);

    const float scl = 0.5f * (RES - 1);
    const float fx = (px + 1.f) * scl, fy = (py + 1.f) * scl, fz = (pz + 1.f) * scl;
    const float xf = floorf(fx), yf = floorf(fy), zf = floorf(fz);
    const float wx = fx - xf, wy = fy - yf, wz = fz - zf;
    int x0 = min(max((int)xf, 0), RES - 1);
    int y0 = min(max((int)yf, 0), RES - 1);
    int z0 = min(max((int)zf, 0), RES - 1);
    const int x1 = min(x0 + 1, RES - 1);
    const int y1 = min(y0 + 1, RES - 1);
    const int z1 = min(z0 + 1, RES - 1);

    const uint4* Pxy = (const uint4*)planesH;
    const uint4* Pxz = (const uint4*)(planesH + (size_t)HW * CCH);
    const uint4* Pyz = (const uint4*)(planesH + (size_t)2 * HW * CCH);
    const uint4* Lx = (const uint4*)linesH;
    const uint4* Ly = (const uint4*)(linesH + (size_t)RES * CCH);
    const uint4* Lz = (const uint4*)(linesH + (size_t)2 * RES * CCH);

    float2 acc[14];
    #pragma unroll
    for (int f = 0; f < 14; ++f) acc[f] = make_float2(0.f, 0.f);

    do_half(Pxy, Lz, y0*RES+x0, y0*RES+x1, y1*RES+x0, y1*RES+x1, z0, z1, wx, wy, wz, 0,  0, bp, acc);
    do_half(Pxy, Lz, y0*RES+x0, y0*RES+x1, y1*RES+x0, y1*RES+x1, z0, z1, wx, wy, wz, 1,  0, bp, acc);
    do_half(Pxz, Ly, z0*RES+x0, z0*RES+x1, z1*RES+x0, z1*RES+x1, y0, y1, wx, wz, wy, 0, 16, bp, acc);
    do_half(Pxz, Ly, z0*RES+x0, z0*RES+x1, z1*RES+x0, z1*RES+x1, y0, y1, wx, wz, wy, 1, 16, bp, acc);
    do_half(Pyz, Lx, z0*RES+y0, z0*RES+y1, z1*RES+y0, z1*RES+y1, x0, x1, wy, wz, wx, 0, 32, bp, acc);
    do_half(Pyz, Lx, z0*RES+y0, z0*RES+y1, z1*RES+y0, z1*RES+y1, x0, x1, wy, wz, wx, 1, 32, bp, acc);

    // stage results + original indices in LDS
    const int sbase = tid * FD;
    #pragma unroll
    for (int f = 0; f < 14; ++f) {
        s_out[sbase + 2*f] = acc[f].x;
        if (2*f + 1 < FD) s_out[sbase + 2*f + 1] = acc[f].y;
    }
    s_oi[tid] = oi;
    __syncthreads();

    // coalesced row stores: each wave writes 64 of the block's points,
    // 2 points per store instruction (lanes 0-26 -> point p, lanes 32-58 -> p+1).
    const int wid  = tid >> 6;
    const int lane = tid & 63;
    const int sub  = lane >> 5;       // which point of the pair
    const int col  = lane & 31;       // dword within the 27-dword row
    if (col < FD) {
        #pragma unroll
        for (int it = 0; it < 32; ++it) {
            const int p = wid * 64 + it * 2 + sub;
            const int o = s_oi[p];
            out[(size_t)o * FD + col] = s_out[p * FD + col];
        }
    }
}

// ---------------- fallback (no workspace) ----------------
__device__ __forceinline__ float bilerp(const float* __restrict__ p,
                                        int o00, int o01, int o10, int o11,
                                        float wc, float wr) {
    float v00 = p[o00], v01 = p[o01], v10 = p[o10], v11 = p[o11];
    float top = v00 + wc * (v01 - v00);
    float bot = v10 + wc * (v11 - v10);
    return top + wr * (bot - top);
}

__global__ __launch_bounds__(BLK) void vm_eval_fallback(
    const float* __restrict__ pts,
    const float* __restrict__ pxy, const float* __restrict__ pyz, const float* __restrict__ pxz,
    const float* __restrict__ vx, const float* __restrict__ vy, const float* __restrict__ vz,
    const float* __restrict__ basis, float* __restrict__ out) {
    const long long i = (long long)blockIdx.x * BLK + threadIdx.x;
    const float px = pts[i*3], py = pts[i*3+1], pz = pts[i*3+2];
    const float scl = 0.5f * (RES - 1);
    const float fx = (px + 1.f) * scl, fy = (py + 1.f) * scl, fz = (pz + 1.f) * scl;
    const float xf = floorf(fx), yf = floorf(fy), zf = floorf(fz);
    const float wx = fx - xf, wy = fy - yf, wz = fz - zf;
    int x0 = min(max((int)xf, 0), RES - 1);
    int y0 = min(max((int)yf, 0), RES - 1);
    int z0 = min(max((int)zf, 0), RES - 1);
    const int x1 = min(x0+1, RES-1), y1 = min(y0+1, RES-1), z1 = min(z0+1, RES-1);
    float acc[FD];
    #pragma unroll
    for (int f = 0; f < FD; ++f) acc[f] = 0.f;
    #pragma unroll 4
    for (int c = 0; c < CCH; ++c) {
        const float* a = pxy + c * HW;
        const float* b = pxz + c * HW;
        const float* d = pyz + c * HW;
        float lz = vz[c*RES+z0]; lz += wz * (vz[c*RES+z1] - lz);
        float ly = vy[c*RES+y0]; ly += wy * (vy[c*RES+y1] - ly);
        float lx = vx[c*RES+x0]; lx += wx * (vx[c*RES+x1] - lx);
        const float fa = bilerp(a, y0*RES+x0, y0*RES+x1, y1*RES+x0, y1*RES+x1, wx, wy) * lz;
        const float fb = bilerp(b, z0*RES+x0, z0*RES+x1, z1*RES+x0, z1*RES+x1, wx, wz) * ly;
        const float fc = bilerp(d, z0*RES+y0, z0*RES+y1, z1*RES+y0, z1*RES+y1, wy, wz) * lx;
        #pragma unroll
        for (int f = 0; f < FD; ++f)
            acc[f] += fa * basis[c*FD+f] + fb * basis[(CCH+c)*FD+f] + fc * basis[(2*CCH+c)*FD+f];
    }
    float* op = out + i * FD;
    #pragma unroll
    for (int f = 0; f < FD; ++f) op[f] = acc[f];
}

extern "C" void kernel_launch(void* const* d_in, const int* in_sizes, int n_in,
                              void* d_out, int out_size, void* d_ws, size_t ws_size,
                              hipStream_t stream) {
    const float* pts   = (const float*)d_in[0];
    const float* pxy   = (const float*)d_in[1];
    const float* pyz   = (const float*)d_in[2];
    const float* pxz   = (const float*)d_in[3];
    const float* vx    = (const float*)d_in[4];
    const float* vy    = (const float*)d_in[5];
    const float* vz    = (const float*)d_in[6];
    const float* basis = (const float*)d_in[7];
    float* out = (float*)d_out;

    if (ws_size < WS_NEED) {
        vm_eval_fallback<<<NPTS / BLK, BLK, 0, stream>>>(pts, pxy, pyz, pxz, vx, vy, vz, basis, out);
        return;
    }

    uint8_t* w = (uint8_t*)d_ws;
    __half*   planesH = (__half*)(w + WS_PLANEH);
    __half*   linesH  = (__half*)(w + WS_LINEH);
    float2*   bpad    = (float2*)(w + WS_BPAD);
    unsigned* chist   = (unsigned*)(w + WS_CHIST);
    unsigned* cursor  = (unsigned*)(w + WS_CURSOR);
    float4*   sorted  = (float4*)(w + WS_SORTED);

    hipMemsetAsync(chist, 0, (size_t)NCELL * 4, stream);
    prep_kernel<<<HIST_BLOCKS + PLANE_BLOCKS + LINE_BLOCKS + 1, BLK, 0, stream>>>(
        pts, pxy, pxz, pyz, vx, vy, vz, basis, planesH, linesH, bpad, chist);
    scan_kernel<<<1, NCELL, 0, stream>>>(chist, cursor);
    scatter_kernel<<<HIST_BLOCKS, BLK, 0, stream>>>(pts, cursor, sorted);
    eval_kernel<<<NPTS / BLK, BLK, 0, stream>>>(sorted, planesH, linesH, bpad, out);
}

// Round 9
// 198.977 us; speedup vs baseline: 4.9830x; 1.1388x over previous
//
#include <hip/hip_runtime.h>
#include <hip/hip_fp16.h>
#include <stdint.h>

// VM-factorized voxel grid: N pts -> 48 feats (3 planes x 16ch) -> 27 outputs.
// Pipeline: memset coarse-hist(512) -> prep (planes/lines -> fp16 channel-last,
// basis -> MFMA B-frags, coarse hist) -> scan -> scatter (LDS rank, contiguous runs)
// -> eval: 2 lanes/point, fp16 gathers, f32 interp, 3x mfma_f32_32x32x16_f16
// (32x48 . 48x27 per wave-tile), LDS-staged coalesced row stores.

constexpr int NPTS = 2097152;
constexpr int CCH  = 16;
constexpr int RES  = 320;
constexpr long long HW = (long long)RES * RES;   // 102400
constexpr int FD   = 27;
constexpr int BLK  = 256;
constexpr int NCELL = 512;                       // 8^3 coarse Morton cells
constexpr int PTS_PER_SORTBLK = 4096;            // 256 thr x 16 pts

constexpr int HIST_BLOCKS = NPTS / PTS_PER_SORTBLK;   // 512
constexpr int PLANE_BLOCKS = 1200;               // 3 * 400
constexpr int LINE_BLOCKS = 4;

// ---- workspace layout (bytes), all 16B-aligned ----
constexpr size_t WS_PLANEH = 0;                                   // 3*HW*16*2 = 9,830,400
constexpr size_t WS_LINEH  = WS_PLANEH + 3ull*HW*CCH*2;           // 30,720
constexpr size_t WS_BFRAG  = WS_LINEH + 3ull*RES*CCH*2;           // 3*64*8*2 = 3,072
constexpr size_t WS_CHIST  = WS_BFRAG + 3072;                     // 2,048
constexpr size_t WS_CURSOR = WS_CHIST + (size_t)NCELL*4;          // 2,048
constexpr size_t WS_SORTED = WS_CURSOR + (size_t)NCELL*4;         // N*16
constexpr size_t WS_NEED   = WS_SORTED + (size_t)NPTS*16;         // ~43.4 MB

typedef _Float16 half8 __attribute__((ext_vector_type(8)));
typedef float f32x16 __attribute__((ext_vector_type(16)));

// ---------------- helpers ----------------
__device__ __forceinline__ unsigned spread3(unsigned v) {
    return (v & 1u) | ((v & 2u) << 2) | ((v & 4u) << 4);
}
__device__ __forceinline__ int cell_key8(float px, float py, float pz) {
    int cx = min(max((int)((px + 1.f) * 4.f), 0), 7);
    int cy = min(max((int)((py + 1.f) * 4.f), 0), 7);
    int cz = min(max((int)((pz + 1.f) * 4.f), 0), 7);
    return (int)(spread3((unsigned)cx) | (spread3((unsigned)cy) << 1) | (spread3((unsigned)cz) << 2));
}

__device__ __forceinline__ float2 pk_mul(float2 a, float2 b) {
    float2 d; asm("v_pk_mul_f32 %0, %1, %2" : "=v"(d) : "v"(a), "v"(b)); return d;
}
__device__ __forceinline__ float2 pk_fma(float2 a, float2 b, float2 c) {
    float2 d; asm("v_pk_fma_f32 %0, %1, %2, %3" : "=v"(d) : "v"(a), "v"(b), "v"(c)); return d;
}

__device__ __forceinline__ float2 h2f(unsigned u) {
    __half2 h = *(__half2*)&u;
    return __half22float2(h);
}
__device__ __forceinline__ unsigned lane_of(uint4 q, int j) {
    return j == 0 ? q.x : (j == 1 ? q.y : (j == 2 ? q.z : q.w));
}

// ---------------- prep: coarse hist + planes/lines fp16 + basis B-frags ----------------
__global__ __launch_bounds__(BLK) void prep_kernel(
    const float* __restrict__ pts,
    const float* __restrict__ pxy, const float* __restrict__ pxz, const float* __restrict__ pyz,
    const float* __restrict__ vx, const float* __restrict__ vy, const float* __restrict__ vz,
    const float* __restrict__ basis,
    __half* __restrict__ planesH, __half* __restrict__ linesH, __half* __restrict__ bfragH,
    unsigned* __restrict__ chist) {
    __shared__ unsigned lh[NCELL];
    const int bid = blockIdx.x;
    const int tid = threadIdx.x;
    if (bid < HIST_BLOCKS) {                // coarse histogram, 4096 pts/block
        lh[tid] = 0u; lh[tid + 256] = 0u;
        __syncthreads();
        const float4* p4 = ((const float4*)pts) + (size_t)bid * 3072;
        #pragma unroll
        for (int g = 0; g < 4; ++g) {
            const float4 a = p4[tid*12 + g*3 + 0];
            const float4 b = p4[tid*12 + g*3 + 1];
            const float4 c = p4[tid*12 + g*3 + 2];
            atomicAdd(&lh[cell_key8(a.x, a.y, a.z)], 1u);
            atomicAdd(&lh[cell_key8(a.w, b.x, b.y)], 1u);
            atomicAdd(&lh[cell_key8(b.z, b.w, c.x)], 1u);
            atomicAdd(&lh[cell_key8(c.y, c.z, c.w)], 1u);
        }
        __syncthreads();
        if (lh[tid])       atomicAdd(&chist[tid],       lh[tid]);
        if (lh[tid + 256]) atomicAdd(&chist[tid + 256], lh[tid + 256]);
    } else if (bid < HIST_BLOCKS + PLANE_BLOCKS) {   // planes -> fp16 channel-last
        const int pb = bid - HIST_BLOCKS;
        const int plane = pb / 400;
        const int texel = (pb % 400) * BLK + tid;
        const float* src = (plane == 0) ? pxy : (plane == 1 ? pxz : pyz);
        union { ushort u[16]; uint4 q[2]; } pk;
        #pragma unroll
        for (int c = 0; c < CCH; ++c)
            pk.u[c] = __half_as_ushort(__float2half(src[(size_t)c * HW + texel]));
        uint4* dst = (uint4*)(planesH + ((size_t)plane * HW + texel) * CCH);
        dst[0] = pk.q[0]; dst[1] = pk.q[1];
    } else if (bid < HIST_BLOCKS + PLANE_BLOCKS + LINE_BLOCKS) {  // lines
        const int idx = (bid - HIST_BLOCKS - PLANE_BLOCKS) * BLK + tid;
        if (idx >= 3 * RES) return;
        const int axis = idx / RES, t = idx % RES;
        const float* src = (axis == 0) ? vx : (axis == 1 ? vy : vz);
        union { ushort u[16]; uint4 q[2]; } pk;
        #pragma unroll
        for (int c = 0; c < CCH; ++c)
            pk.u[c] = __half_as_ushort(__float2half(src[c * RES + t]));
        uint4* dst = (uint4*)(linesH + ((size_t)axis * RES + t) * CCH);
        dst[0] = pk.q[0]; dst[1] = pk.q[1];
    } else {   // basis (48,27) -> MFMA B-frag fp16: bfrag[r][lane][j] = basis[r*16+(l>>5)*8+j][l&31]
        if (tid < 192) {
            const int r = tid >> 6, l = tid & 63;
            const int col = l & 31, kb = l >> 5;
            __half* dst = bfragH + tid * 8;
            #pragma unroll
            for (int j = 0; j < 8; ++j) {
                float v = (col < FD) ? basis[(r * 16 + kb * 8 + j) * FD + col] : 0.f;
                dst[j] = __float2half(v);
            }
        }
    }
}

// ---------------- scan: exclusive scan of 512 coarse-cell counts -> cursor ----------------
__global__ __launch_bounds__(NCELL) void scan_kernel(const unsigned* __restrict__ chist,
                                                     unsigned* __restrict__ cursor) {
    __shared__ unsigned l[NCELL];
    const int t = threadIdx.x;
    const unsigned v = chist[t];
    l[t] = v;
    __syncthreads();
    for (int o = 1; o < NCELL; o <<= 1) {
        unsigned u = (t >= o) ? l[t - o] : 0u;
        __syncthreads();
        l[t] += u;
        __syncthreads();
    }
    cursor[t] = l[t] - v;   // exclusive
}

// ---------------- scatter: LDS rank + 1 global atomic per (block,cell) ----------------
__global__ __launch_bounds__(BLK) void scatter_kernel(const float* __restrict__ pts,
                                                      unsigned* __restrict__ cursor,
                                                      float4* __restrict__ sorted) {
    __shared__ unsigned lh[NCELL];
    __shared__ unsigned lb[NCELL];
    const int bid = blockIdx.x;
    const int tid = threadIdx.x;
    lh[tid] = 0u; lh[tid + 256] = 0u;
    __syncthreads();
    const float4* p4 = ((const float4*)pts) + (size_t)bid * 3072;
    unsigned kr[16];   // (key<<16) | rank
    #pragma unroll
    for (int g = 0; g < 4; ++g) {
        const float4 a = p4[tid*12 + g*3 + 0];
        const float4 b = p4[tid*12 + g*3 + 1];
        const float4 c = p4[tid*12 + g*3 + 2];
        int k; unsigned r;
        k = cell_key8(a.x, a.y, a.z); r = atomicAdd(&lh[k], 1u); kr[g*4+0] = ((unsigned)k << 16) | r;
        k = cell_key8(a.w, b.x, b.y); r = atomicAdd(&lh[k], 1u); kr[g*4+1] = ((unsigned)k << 16) | r;
        k = cell_key8(b.z, b.w, c.x); r = atomicAdd(&lh[k], 1u); kr[g*4+2] = ((unsigned)k << 16) | r;
        k = cell_key8(c.y, c.z, c.w); r = atomicAdd(&lh[k], 1u); kr[g*4+3] = ((unsigned)k << 16) | r;
    }
    __syncthreads();
    lb[tid]       = atomicAdd(&cursor[tid],       lh[tid]);
    lb[tid + 256] = atomicAdd(&cursor[tid + 256], lh[tid + 256]);
    __syncthreads();
    const int ibase = bid * PTS_PER_SORTBLK + tid * 16;
    #pragma unroll
    for (int g = 0; g < 4; ++g) {
        const float4 a = p4[tid*12 + g*3 + 0];
        const float4 b = p4[tid*12 + g*3 + 1];
        const float4 c = p4[tid*12 + g*3 + 2];
        unsigned e;
        e = kr[g*4+0]; sorted[lb[e >> 16] + (e & 0xffffu)] = make_float4(a.x, a.y, a.z, __int_as_float(ibase + g*4 + 0));
        e = kr[g*4+1]; sorted[lb[e >> 16] + (e & 0xffffu)] = make_float4(a.w, b.x, b.y, __int_as_float(ibase + g*4 + 1));
        e = kr[g*4+2]; sorted[lb[e >> 16] + (e & 0xffffu)] = make_float4(b.z, b.w, c.x, __int_as_float(ibase + g*4 + 2));
        e = kr[g*4+3]; sorted[lb[e >> 16] + (e & 0xffffu)] = make_float4(c.y, c.z, c.w, __int_as_float(ibase + g*4 + 3));
    }
}

// ---------------- eval ----------------
// Per lane: interpolate 8 channels (one plane-half, h = lane>>5) of its point
// (lane&31) in f32, emit as fp16 MFMA A-fragment slot.
__device__ __forceinline__ half8 interp8(const uint4* __restrict__ P, const uint4* __restrict__ L,
                                         int t00, int t01, int t10, int t11, int l0, int l1,
                                         float wc, float wr, float lw, int h) {
    const uint4 c00 = P[2*t00 + h], c01 = P[2*t01 + h];
    const uint4 c10 = P[2*t10 + h], c11 = P[2*t11 + h];
    const uint4 la4 = L[2*l0 + h],  lb4 = L[2*l1 + h];
    const float w00 = (1.f - wc) * (1.f - wr), w01 = wc * (1.f - wr);
    const float w10 = (1.f - wc) * wr,         w11 = wc * wr;
    const float2 w00_2 = make_float2(w00, w00), w01_2 = make_float2(w01, w01);
    const float2 w10_2 = make_float2(w10, w10), w11_2 = make_float2(w11, w11);
    const float2 lw2   = make_float2(lw, lw),   mlw2  = make_float2(1.f - lw, 1.f - lw);
    union { half8 v; __half2 h2[4]; } af;
    #pragma unroll
    for (int q = 0; q < 4; ++q) {
        float2 s = pk_mul(h2f(lane_of(c00, q)), w00_2);
        s = pk_fma(h2f(lane_of(c01, q)), w01_2, s);
        s = pk_fma(h2f(lane_of(c10, q)), w10_2, s);
        s = pk_fma(h2f(lane_of(c11, q)), w11_2, s);
        float2 l = pk_mul(h2f(lane_of(la4, q)), mlw2);
        l = pk_fma(h2f(lane_of(lb4, q)), lw2, l);
        s = pk_mul(s, l);
        af.h2[q] = __float22half2_rn(s);
    }
    return af.v;
}

__global__ __launch_bounds__(BLK) void eval_kernel(
    const float4* __restrict__ sorted,
    const __half* __restrict__ planesH,
    const __half* __restrict__ linesH,
    const __half* __restrict__ bfragH,
    float* __restrict__ out) {
    __shared__ float s_out[BLK * FD];   // 27648 B
    __shared__ int   s_oi[BLK];         // 1024 B
    constexpr int NBLK = NPTS / BLK;            // 8192
    constexpr int CHUNK = NBLK / 8;             // 1024
    const int bid = blockIdx.x;
    const int tid = threadIdx.x;
    const int swz = (bid & 7) * CHUNK + (bid >> 3);   // contiguous sorted range per XCD
    const int wid = tid >> 6, lane = tid & 63;
    const int pcol = lane & 31, kb = lane >> 5;

    // B fragments (basis rows 0-15 / 16-31 / 32-47), held in registers
    union BU { uint4 u; half8 h; } b0u, b1u, b2u;
    const uint4* bf = (const uint4*)bfragH;
    b0u.u = bf[lane]; b1u.u = bf[64 + lane]; b2u.u = bf[128 + lane];

    const uint4* Pxy = (const uint4*)planesH;
    const uint4* Pxz = (const uint4*)(planesH + (size_t)HW * CCH);
    const uint4* Pyz = (const uint4*)(planesH + (size_t)2 * HW * CCH);
    const uint4* Lx = (const uint4*)linesH;
    const uint4* Ly = (const uint4*)(linesH + (size_t)RES * CCH);
    const uint4* Lz = (const uint4*)(linesH + (size_t)2 * RES * CCH);

    const int blockbase = swz * BLK;
    #pragma unroll
    for (int t = 0; t < 2; ++t) {
        const int tbase = wid * 64 + t * 32;          // tile base within block
        const float4 pt = sorted[blockbase + tbase + pcol];
        const float px = pt.x, py = pt.y, pz = pt.z;

        const float scl = 0.5f * (RES - 1);
        const float fx = (px + 1.f) * scl, fy = (py + 1.f) * scl, fz = (pz + 1.f) * scl;
        const float xf = floorf(fx), yf = floorf(fy), zf = floorf(fz);
        const float wx = fx - xf, wy = fy - yf, wz = fz - zf;
        int x0 = min(max((int)xf, 0), RES - 1);
        int y0 = min(max((int)yf, 0), RES - 1);
        int z0 = min(max((int)zf, 0), RES - 1);
        const int x1 = min(x0 + 1, RES - 1);
        const int y1 = min(y0 + 1, RES - 1);
        const int z1 = min(z0 + 1, RES - 1);

        f32x16 acc;
        #pragma unroll
        for (int r = 0; r < 16; ++r) acc[r] = 0.f;

        half8 a0 = interp8(Pxy, Lz, y0*RES+x0, y0*RES+x1, y1*RES+x0, y1*RES+x1, z0, z1, wx, wy, wz, kb);
        acc = __builtin_amdgcn_mfma_f32_32x32x16_f16(a0, b0u.h, acc, 0, 0, 0);
        half8 a1 = interp8(Pxz, Ly, z0*RES+x0, z0*RES+x1, z1*RES+x0, z1*RES+x1, y0, y1, wx, wz, wy, kb);
        acc = __builtin_amdgcn_mfma_f32_32x32x16_f16(a1, b1u.h, acc, 0, 0, 0);
        half8 a2 = interp8(Pyz, Lx, z0*RES+y0, z0*RES+y1, z1*RES+y0, z1*RES+y1, x0, x1, wy, wz, wx, kb);
        acc = __builtin_amdgcn_mfma_f32_32x32x16_f16(a2, b2u.h, acc, 0, 0, 0);

        // D layout: col = lane&31, row = (reg&3) + 8*(reg>>2) + 4*(lane>>5)
        if (pcol < FD) {
            #pragma unroll
            for (int r = 0; r < 16; ++r) {
                const int row = (r & 3) + 8 * (r >> 2) + 4 * kb;
                s_out[(tbase + row) * FD + pcol] = acc[r];
            }
        }
        if (kb == 0) s_oi[tbase + pcol] = __float_as_int(pt.w);
    }
    __syncthreads();

    // coalesced row stores: each wave writes 64 of the block's points,
    // 2 points per store instruction (lanes 0-26 -> point p, lanes 32-58 -> p+1).
    const int sub = lane >> 5;
    const int col = lane & 31;
    if (col < FD) {
        #pragma unroll
        for (int it = 0; it < 32; ++it) {
            const int p = wid * 64 + it * 2 + sub;
            const int o = s_oi[p];
            out[(size_t)o * FD + col] = s_out[p * FD + col];
        }
    }
}

// ---------------- fallback (no workspace) ----------------
__device__ __forceinline__ float bilerp(const float* __restrict__ p,
                                        int o00, int o01, int o10, int o11,
                                        float wc, float wr) {
    float v00 = p[o00], v01 = p[o01], v10 = p[o10], v11 = p[o11];
    float top = v00 + wc * (v01 - v00);
    float bot = v10 + wc * (v11 - v10);
    return top + wr * (bot - top);
}

__global__ __launch_bounds__(BLK) void vm_eval_fallback(
    const float* __restrict__ pts,
    const float* __restrict__ pxy, const float* __restrict__ pyz, const float* __restrict__ pxz,
    const float* __restrict__ vx, const float* __restrict__ vy, const float* __restrict__ vz,
    const float* __restrict__ basis, float* __restrict__ out) {
    const long long i = (long long)blockIdx.x * BLK + threadIdx.x;
    const float px = pts[i*3], py = pts[i*3+1], pz = pts[i*3+2];
    const float scl = 0.5f * (RES - 1);
    const float fx = (px + 1.f) * scl, fy = (py + 1.f) * scl, fz = (pz + 1.f) * scl;
    const float xf = floorf(fx), yf = floorf(fy), zf = floorf(fz);
    const float wx = fx - xf, wy = fy - yf, wz = fz - zf;
    int x0 = min(max((int)xf, 0), RES - 1);
    int y0 = min(max((int)yf, 0), RES - 1);
    int z0 = min(max((int)zf, 0), RES - 1);
    const int x1 = min(x0+1, RES-1), y1 = min(y0+1, RES-1), z1 = min(z0+1, RES-1);
    float acc[FD];
    #pragma unroll
    for (int f = 0; f < FD; ++f) acc[f] = 0.f;
    #pragma unroll 4
    for (int c = 0; c < CCH; ++c) {
        const float* a = pxy + c * HW;
        const float* b = pxz + c * HW;
        const float* d = pyz + c * HW;
        float lz = vz[c*RES+z0]; lz += wz * (vz[c*RES+z1] - lz);
        float ly = vy[c*RES+y0]; ly += wy * (vy[c*RES+y1] - ly);
        float lx = vx[c*RES+x0]; lx += wx * (vx[c*RES+x1] - lx);
        const float fa = bilerp(a, y0*RES+x0, y0*RES+x1, y1*RES+x0, y1*RES+x1, wx, wy) * lz;
        const float fb = bilerp(b, z0*RES+x0, z0*RES+x1, z1*RES+x0, z1*RES+x1, wx, wz) * ly;
        const float fc = bilerp(d, z0*RES+y0, z0*RES+y1, z1*RES+y0, z1*RES+y1, wy, wz) * lx;
        #pragma unroll
        for (int f = 0; f < FD; ++f)
            acc[f] += fa * basis[c*FD+f] + fb * basis[(CCH+c)*FD+f] + fc * basis[(2*CCH+c)*FD+f];
    }
    float* op = out + i * FD;
    #pragma unroll
    for (int f = 0; f < FD; ++f) op[f] = acc[f];
}

extern "C" void kernel_launch(void* const* d_in, const int* in_sizes, int n_in,
                              void* d_out, int out_size, void* d_ws, size_t ws_size,
                              hipStream_t stream) {
    const float* pts   = (const float*)d_in[0];
    const float* pxy   = (const float*)d_in[1];
    const float* pyz   = (const float*)d_in[2];
    const float* pxz   = (const float*)d_in[3];
    const float* vx    = (const float*)d_in[4];
    const float* vy    = (const float*)d_in[5];
    const float* vz    = (const float*)d_in[6];
    const float* basis = (const float*)d_in[7];
    float* out = (float*)d_out;

    if (ws_size < WS_NEED) {
        vm_eval_fallback<<<NPTS / BLK, BLK, 0, stream>>>(pts, pxy, pyz, pxz, vx, vy, vz, basis, out);
        return;
    }

    uint8_t* w = (uint8_t*)d_ws;
    __half*   planesH = (__half*)(w + WS_PLANEH);
    __half*   linesH  = (__half*)(w + WS_LINEH);
    __half*   bfragH  = (__half*)(w + WS_BFRAG);
    unsigned* chist   = (unsigned*)(w + WS_CHIST);
    unsigned* cursor  = (unsigned*)(w + WS_CURSOR);
    float4*   sorted  = (float4*)(w + WS_SORTED);

    hipMemsetAsync(chist, 0, (size_t)NCELL * 4, stream);
    prep_kernel<<<HIST_BLOCKS + PLANE_BLOCKS + LINE_BLOCKS + 1, BLK, 0, stream>>>(
        pts, pxy, pxz, pyz, vx, vy, vz, basis, planesH, linesH, bfragH, chist);
    scan_kernel<<<1, NCELL, 0, stream>>>(chist, cursor);
    scatter_kernel<<<HIST_BLOCKS, BLK, 0, stream>>>(pts, cursor, sorted);
    eval_kernel<<<NPTS / BLK, BLK, 0, stream>>>(sorted, planesH, linesH, bfragH, out);
}